// Round 7
// baseline (2939.106 us; speedup 1.0000x reference)
//
#include <hip/hip_runtime.h>

// Perona-Malik diffusion, 500 iters. Round-11 = Round-10 with the compile
// fix: __hip_atomic_thread_fence -> __builtin_amdgcn_fence(order, "agent").
// ONE hipLaunchCooperativeKernel runs all 50 supersteps. Coeffs live in
// registers (loaded once); interior values persist in registers/LDS across
// supersteps (f32 store/load round-trip is exact -> skipping it is
// bit-identical); only halo units reload from the global ping-pong.
// Neighbor-only sync: release(agent) fence + per-block flag after interior
// write; spin on <=8 neighbor flags + acquire(agent) fence before halo read
// (fences handle XCD L2 non-coherence). The wait before superstep k's halo
// read also guards the end-of-superstep-k write of the same buffer (WAR).
// Host falls back to the verified R7 relaunch loop if cooperative fails.

#define HH 512
#define WW 512
#define NB 2
static constexpr float LAM   = 0.24f;
static constexpr float KCOND = 0.03f;
static constexpr float DEPS_ = 0.1f;
static constexpr int IMG      = HH * WW;
static constexpr int N_DEPTH  = NB * IMG;
static constexpr int CV_PER_B = (HH - 1) * WW;
static constexpr int CH_PER_B = HH * (WW - 1);
static constexpr int N_CV     = NB * CV_PER_B;
static constexpr int N_CH     = NB * CH_PER_B;

static constexpr int T_FUSE = 10, NSS = 50;       // 50 x 10 = 500
static constexpr int TILE_W = 64, TILE_H = 32;
static constexpr int HALO_X = 12, HALO_Y = 10;
static constexpr int RW = TILE_W + 2 * HALO_X;    // 88
static constexpr int RH = TILE_H + 2 * HALO_Y;    // 52
static constexpr int NQ_ROW = RW / 4;             // 22
static constexpr int NQUAD  = NQ_ROW * RH;        // 1144 (fallback)
static constexpr int SSZ    = (RH + 2) * RW;      // fallback layout (4752)

// fast path: 4x2 units, one per thread (R7 geometry, 495us verified)
static constexpr int NU_ROW = RW / 4;              // 22 units per row-pair
static constexpr int NU_COL = RH / 2;              // 26 row-pairs
static constexpr int NUNIT  = NU_ROW * NU_COL;     // 572
static constexpr int NTF    = 576;                 // 9 waves

// fast-path LDS layout (floats), per ping-pong buffer (R7):
static constexpr int S_LDS    = 92;
static constexpr int ROWS_SZ  = (RH + 2) * S_LDS;       // 4968
static constexpr int TRASH_OFF = ROWS_SZ;               // 4968
static constexpr int EDGE_OFF = ROWS_SZ + S_LDS;        // 5060 (16B aligned)
static constexpr int EDGE_ENT = 580;                    // entries 0..577 used
static constexpr int BUF_SZ   = EDGE_OFF + EDGE_ENT * 4; // 7380

// coefficient planes (per block), R7 layout
static constexpr int CVW = RW;                     // 88
static constexpr int CV_SZ = (RH + 1) * CVW;       // 4664
static constexpr int CHW = RW + 8;                 // 96
static constexpr int CH_SZ = RH * CHW;             // 4992
static constexpr int BLOB_BLK = CV_SZ + CH_SZ;     // 9656 floats/block

// fallback path (round-2 verified): 256 threads, 5 quads/thread
static constexpr int QPT_F = 5;

// ---- monotone float<->uint key for atomic min ----
__device__ __forceinline__ unsigned fkey(float f) {
    unsigned u = __float_as_uint(f);
    return (u & 0x80000000u) ? ~u : (u | 0x80000000u);
}
__device__ __forceinline__ float kinv(unsigned k) {
    return __uint_as_float((k & 0x80000000u) ? (k & 0x7fffffffu) : ~k);
}

__global__ void init_key_kernel(unsigned* key, unsigned* flags) {
    if (threadIdx.x == 0) *key = 0xFFFFFFFFu;
    flags[threadIdx.x] = 0u;   // 256 threads, one flag per persistent block
}

__global__ void min_kernel(const float* __restrict__ x, unsigned* key) {
    float m = 3.4e38f;
    for (int idx = blockIdx.x * blockDim.x + threadIdx.x; idx < N_DEPTH;
         idx += gridDim.x * blockDim.x)
        m = fminf(m, x[idx]);
    for (int off = 32; off > 0; off >>= 1) m = fminf(m, __shfl_down(m, off, 64));
    __shared__ float sm[4];
    int lane = threadIdx.x & 63, wv = threadIdx.x >> 6;
    if (lane == 0) sm[wv] = m;
    __syncthreads();
    if (threadIdx.x == 0) {
        float mm = fminf(fminf(sm[0], sm[1]), fminf(sm[2], sm[3]));
        atomicMin(key, fkey(mm));
    }
}

__global__ void coeff_kernel(const float* __restrict__ g, float* __restrict__ cv,
                             float* __restrict__ chh) {
    int idx = blockIdx.x * blockDim.x + threadIdx.x;
    constexpr float kk = KCOND * KCOND;
    if (idx < N_CV) {
        int b = idx / CV_PER_B;
        int r = idx - b * CV_PER_B;
        int i = r >> 9, j = r & (WW - 1);
        const float* gb = g + b * 3 * IMG + i * WW + j;
        float s = 0.f;
#pragma unroll
        for (int c = 0; c < 3; ++c) s += fabsf(gb[c * IMG + WW] - gb[c * IMG]);
        float m = s / 3.0f;
        cv[idx] = 1.0f / (1.0f + (m * m) / kk);
    } else if (idx < N_CV + N_CH) {
        int t = idx - N_CV;
        int b = t / CH_PER_B;
        int r = t - b * CH_PER_B;
        int i = r / (WW - 1);
        int j = r - i * (WW - 1);
        const float* gb = g + b * 3 * IMG + i * WW + j;
        float s = 0.f;
#pragma unroll
        for (int c = 0; c < 3; ++c) s += fabsf(gb[c * IMG + 1] - gb[c * IMG]);
        float m = s / 3.0f;
        chh[t] = 1.0f / (1.0f + (m * m) / kk);
    }
}

// One-time: bake predicated L*cv / L*ch into dense per-block planes.
__global__ __launch_bounds__(256) void prep_planes(const float* __restrict__ cv_g,
                                                   const float* __restrict__ ch_g,
                                                   float* __restrict__ blob) {
    const int blk = blockIdx.x;
    const int b   = blk >> 7, t = blk & 127;
    const int y0  = (t >> 3) * TILE_H;
    const int x0  = (t & 7) * TILE_W;
    const float* cvb = cv_g + b * CV_PER_B;
    const float* chb = ch_g + b * CH_PER_B;
    float* pv = blob + blk * BLOB_BLK;
    float* ph = pv + CV_SZ;
    for (int i = threadIdx.x; i < CV_SZ; i += 256) {
        int rr = i / CVW, x = i - rr * CVW;
        int gy = y0 - HALO_Y + rr, gx = x0 - HALO_X + x;
        bool ok = (rr >= 1) && (rr <= RH - 1) && (gy >= 1) && (gy <= HH - 1) &&
                  (gx >= 0) && (gx < WW);
        pv[i] = ok ? LAM * cvb[(gy - 1) * WW + gx] : 0.f;
    }
    for (int i = threadIdx.x; i < CH_SZ; i += 256) {
        int rr = i / CHW, xe = i - rr * CHW;
        int gy = y0 - HALO_Y + rr, gxe = x0 - HALO_X + xe;
        bool ok = (xe >= 1) && (xe <= RW - 1) && (gy >= 0) && (gy < HH) &&
                  (gxe >= 1) && (gxe < WW);
        ph[i] = ok ? LAM * chb[gy * (WW - 1) + (gxe - 1)] : 0.f;
    }
}

// ================= persistent cooperative kernel =================
__global__ __launch_bounds__(NTF, 1) void diffuse_persist(
    const float* __restrict__ initial, float* __restrict__ out_y,
    float* __restrict__ bufA, float* __restrict__ bufB,
    const float* __restrict__ blob, const unsigned* __restrict__ key,
    unsigned* __restrict__ flags) {
    __shared__ float sb[2][BUF_SZ];
    const int blk = blockIdx.x;
    const int b   = blk >> 7, t = blk & 127;
    const int ty  = t >> 3, tx = t & 7;
    const int y0  = ty * TILE_H;
    const int x0  = tx * TILE_W;
    const float* pv = blob + blk * BLOB_BLK;
    const float* ph = pv + CV_SZ;
    const float shift = (kinv(*key) <= DEPS_) ? DEPS_ : 0.f;
    const int tid = threadIdx.x;

    // ---- unit geometry: 4 wide x 2 tall (R7) ----
    const bool act = tid < NUNIT;
    const int  uc  = act ? tid : 0;
    const int  pr  = uc / NU_ROW;
    const int  px  = uc - pr * NU_ROW;
    const int  x   = px * 4;
    const int  r0  = 2 * pr, r1 = r0 + 1;
    int roff0 = (r0 + 1) * S_LDS + x;
    int roff1 = roff0 + S_LDS;
    if (!act) { roff0 = TRASH_OFF + (tid & 3) * 8; roff1 = roff0 + 4; }
    const int e_w  = EDGE_OFF + (tid + 1) * 4;
    const int e_lf = EDGE_OFF + tid * 4 + 2;
    const int e_rt = EDGE_OFF + (tid + 2) * 4;

    const int gy0 = y0 - HALO_Y + r0, gy1 = gy0 + 1;
    const int gx  = x0 - HALO_X + x;
    const bool gx_in = (gx >= 0) && (gx <= WW - 4);
    const bool in0 = act && gx_in && (gy0 >= 0) && (gy0 < HH);
    const bool in1 = act && gx_in && (gy1 >= 0) && (gy1 < HH);
    const int goff0 = in0 ? (gy0 * WW + gx) : 0;
    const int goff1 = in1 ? (gy1 * WW + gx) : 0;
    const bool is_int = act && (r0 >= HALO_Y) && (r1 < HALO_Y + TILE_H) &&
                        (x >= HALO_X) && (x < HALO_X + TILE_W);

    // ---- coefficients ONCE (baked, predicated) ----
    const float am = act ? 1.f : 0.f;
    float ca[4], cm[4], cb[4], h0[5], h1[5];
    {
        float4 a = *reinterpret_cast<const float4*>(&pv[r0 * CVW + x]);
        float4 m = *reinterpret_cast<const float4*>(&pv[r1 * CVW + x]);
        float4 d = *reinterpret_cast<const float4*>(&pv[(r1 + 1) * CVW + x]);
        ca[0] = a.x * am; ca[1] = a.y * am; ca[2] = a.z * am; ca[3] = a.w * am;
        cm[0] = m.x * am; cm[1] = m.y * am; cm[2] = m.z * am; cm[3] = m.w * am;
        cb[0] = d.x * am; cb[1] = d.y * am; cb[2] = d.z * am; cb[3] = d.w * am;
        float4 u = *reinterpret_cast<const float4*>(&ph[r0 * CHW + x]);
        float  u4 = ph[r0 * CHW + x + 4];
        float4 w = *reinterpret_cast<const float4*>(&ph[r1 * CHW + x]);
        float  w4 = ph[r1 * CHW + x + 4];
        h0[0] = u.x * am; h0[1] = u.y * am; h0[2] = u.z * am; h0[3] = u.w * am; h0[4] = u4 * am;
        h1[0] = w.x * am; h1[1] = w.y * am; h1[2] = w.z * am; h1[3] = w.w * am; h1[4] = w4 * am;
    }

    // ---- neighbor flag index (tid<8 -> one of 8 neighbors) ----
    int nbr = -1;
    if (tid < 8) {
        int d  = tid + (tid >= 4 ? 1 : 0);      // 0..8 skipping center(4)
        int dy = d / 3 - 1, dx = d % 3 - 1;
        int ny = ty + dy, nx = tx + dx;
        if (ny >= 0 && ny < 16 && nx >= 0 && nx < 8)
            nbr = (b << 7) + (ny << 3) + nx;
    }

    // ---- superstep-0 full load (+shift) ----
    float v0[4] = {0.f, 0.f, 0.f, 0.f}, v1[4] = {0.f, 0.f, 0.f, 0.f};
    const float* ib = initial + b * IMG;
    if (in0) {
        float4 tv = *reinterpret_cast<const float4*>(ib + goff0);
        v0[0] = tv.x + shift; v0[1] = tv.y + shift; v0[2] = tv.z + shift; v0[3] = tv.w + shift;
    }
    if (in1) {
        float4 tv = *reinterpret_cast<const float4*>(ib + goff1);
        v1[0] = tv.x + shift; v1[1] = tv.y + shift; v1[2] = tv.z + shift; v1[3] = tv.w + shift;
    }

    // guard rows + edge sentinels (once; they stay valid across supersteps)
    for (int i = tid; i < S_LDS; i += NTF) {
        sb[0][i] = 0.f; sb[0][(RH + 1) * S_LDS + i] = 0.f;
        sb[1][i] = 0.f; sb[1][(RH + 1) * S_LDS + i] = 0.f;
    }
    if (tid == 0) {
        float4 z{0.f, 0.f, 0.f, 0.f};
        *reinterpret_cast<float4*>(&sb[0][EDGE_OFF]) = z;
        *reinterpret_cast<float4*>(&sb[1][EDGE_OFF]) = z;
        *reinterpret_cast<float4*>(&sb[0][EDGE_OFF + 577 * 4]) = z;
        *reinterpret_cast<float4*>(&sb[1][EDGE_OFF + 577 * 4]) = z;
    }
    *reinterpret_cast<float4*>(&sb[0][roff0]) = float4{v0[0], v0[1], v0[2], v0[3]};
    *reinterpret_cast<float4*>(&sb[0][roff1]) = float4{v1[0], v1[1], v1[2], v1[3]};
    *reinterpret_cast<float4*>(&sb[0][e_w])   = float4{v0[0], v1[0], v0[3], v1[3]};
    __syncthreads();

    for (int k = 0; k < NSS; ++k) {
        if (k > 0) {
            // wait for the 8 neighbors to have COMPLETED superstep k-1
            if (nbr >= 0) {
                while (__hip_atomic_load(&flags[nbr], __ATOMIC_RELAXED,
                                         __HIP_MEMORY_SCOPE_AGENT) < (unsigned)k)
                    __builtin_amdgcn_s_sleep(2);
            }
            __syncthreads();
            __builtin_amdgcn_fence(__ATOMIC_ACQUIRE, "agent");
            // halo units reload from src_k = buf[(k-1)&1]; interior persists
            const float* srcb = ((k & 1) ? bufA : bufB) + b * IMG;
            if (act && !is_int) {
                float4 t0{0.f, 0.f, 0.f, 0.f}, t1{0.f, 0.f, 0.f, 0.f};
                if (in0) t0 = *reinterpret_cast<const float4*>(srcb + goff0);
                if (in1) t1 = *reinterpret_cast<const float4*>(srcb + goff1);
                v0[0] = t0.x; v0[1] = t0.y; v0[2] = t0.z; v0[3] = t0.w;
                v1[0] = t1.x; v1[1] = t1.y; v1[2] = t1.z; v1[3] = t1.w;
                *reinterpret_cast<float4*>(&sb[0][roff0]) = t0;
                *reinterpret_cast<float4*>(&sb[0][roff1]) = t1;
                *reinterpret_cast<float4*>(&sb[0][e_w]) =
                    float4{v0[0], v1[0], v0[3], v1[3]};
            }
            __syncthreads();
        }

        int cur = 0;
        for (int it = 0; it < T_FUSE; ++it) {
            const float* s = sb[cur];
            float2 lfp = *reinterpret_cast<const float2*>(&s[e_lf]);
            float2 rtp = *reinterpret_cast<const float2*>(&s[e_rt]);
            float4 up = *reinterpret_cast<const float4*>(&s[roff0 - S_LDS]);
            float4 dn = *reinterpret_cast<const float4*>(&s[roff1 + S_LDS]);

            float n0[4], n1[4];
            n0[0] = v0[0] - ca[0] * (v0[0] - up.x) + cm[0] * (v1[0] - v0[0])
                          - h0[0] * (v0[0] - lfp.x) + h0[1] * (v0[1] - v0[0]);
            n0[1] = v0[1] - ca[1] * (v0[1] - up.y) + cm[1] * (v1[1] - v0[1])
                          - h0[1] * (v0[1] - v0[0]) + h0[2] * (v0[2] - v0[1]);
            n0[2] = v0[2] - ca[2] * (v0[2] - up.z) + cm[2] * (v1[2] - v0[2])
                          - h0[2] * (v0[2] - v0[1]) + h0[3] * (v0[3] - v0[2]);
            n0[3] = v0[3] - ca[3] * (v0[3] - up.w) + cm[3] * (v1[3] - v0[3])
                          - h0[3] * (v0[3] - v0[2]) + h0[4] * (rtp.x - v0[3]);
            n1[0] = v1[0] - cm[0] * (v1[0] - v0[0]) + cb[0] * (dn.x - v1[0])
                          - h1[0] * (v1[0] - lfp.y) + h1[1] * (v1[1] - v1[0]);
            n1[1] = v1[1] - cm[1] * (v1[1] - v0[1]) + cb[1] * (dn.y - v1[1])
                          - h1[1] * (v1[1] - v1[0]) + h1[2] * (v1[2] - v1[1]);
            n1[2] = v1[2] - cm[2] * (v1[2] - v0[2]) + cb[2] * (dn.z - v1[2])
                          - h1[2] * (v1[2] - v1[1]) + h1[3] * (v1[3] - v1[2]);
            n1[3] = v1[3] - cm[3] * (v1[3] - v0[3]) + cb[3] * (dn.w - v1[3])
                          - h1[3] * (v1[3] - v1[2]) + h1[4] * (rtp.y - v1[3]);

            int nxt = cur ^ 1;
            float* d = sb[nxt];
            *reinterpret_cast<float4*>(&d[roff0]) = float4{n0[0], n0[1], n0[2], n0[3]};
            *reinterpret_cast<float4*>(&d[roff1]) = float4{n1[0], n1[1], n1[2], n1[3]};
            *reinterpret_cast<float4*>(&d[e_w])   = float4{n0[0], n1[0], n0[3], n1[3]};
            v0[0] = n0[0]; v0[1] = n0[1]; v0[2] = n0[2]; v0[3] = n0[3];
            v1[0] = n1[0]; v1[1] = n1[1]; v1[2] = n1[2]; v1[3] = n1[3];
            cur = nxt;
            __syncthreads();
        }
        // T_FUSE even -> final values live in sb[0]; LDS stays valid for k+1.

        float* dstb = ((k == NSS - 1) ? out_y : ((k & 1) ? bufB : bufA)) + b * IMG;
        if (is_int) {
            float4 o0{v0[0], v0[1], v0[2], v0[3]};
            float4 o1{v1[0], v1[1], v1[2], v1[3]};
            if (k == NSS - 1) {
                o0.x -= shift; o0.y -= shift; o0.z -= shift; o0.w -= shift;
                o1.x -= shift; o1.y -= shift; o1.z -= shift; o1.w -= shift;
            }
            *reinterpret_cast<float4*>(dstb + goff0) = o0;
            *reinterpret_cast<float4*>(dstb + goff1) = o1;
        }
        if (k < NSS - 1) {
            __builtin_amdgcn_fence(__ATOMIC_RELEASE, "agent");
            __syncthreads();
            if (tid == 0)
                __hip_atomic_store(&flags[blk], (unsigned)(k + 1),
                                   __ATOMIC_RELEASE, __HIP_MEMORY_SCOPE_AGENT);
        }
    }
}

// ---------- R7 relaunch step kernel (fallback if cooperative fails) ----------
template <bool ADD_SHIFT, bool SUB_SHIFT>
__global__ __launch_bounds__(NTF, 1) void step_fast(
    const float* __restrict__ src, float* __restrict__ dst,
    const float* __restrict__ blob, const unsigned* __restrict__ key) {
    __shared__ float sb[2][BUF_SZ];
    const int blk = blockIdx.x;
    const int b   = blk >> 7, t = blk & 127;
    const int y0  = (t >> 3) * TILE_H;
    const int x0  = (t & 7) * TILE_W;
    const float* srcb = src + b * IMG;
    const float* pv   = blob + blk * BLOB_BLK;
    const float* ph   = pv + CV_SZ;
    float shift = 0.f;
    if (ADD_SHIFT || SUB_SHIFT) shift = (kinv(*key) <= DEPS_) ? DEPS_ : 0.f;
    const int tid = threadIdx.x;
    const bool act = tid < NUNIT;
    const int  uc  = act ? tid : 0;
    const int  pr  = uc / NU_ROW;
    const int  px  = uc - pr * NU_ROW;
    const int  x   = px * 4;
    const int  r0  = 2 * pr, r1 = r0 + 1;
    int roff0 = (r0 + 1) * S_LDS + x;
    int roff1 = roff0 + S_LDS;
    if (!act) { roff0 = TRASH_OFF + (tid & 3) * 8; roff1 = roff0 + 4; }
    const int e_w  = EDGE_OFF + (tid + 1) * 4;
    const int e_lf = EDGE_OFF + tid * 4 + 2;
    const int e_rt = EDGE_OFF + (tid + 2) * 4;
    const int gy0 = y0 - HALO_Y + r0, gy1 = gy0 + 1;
    const int gx  = x0 - HALO_X + x;
    const bool gx_in = (gx >= 0) && (gx <= WW - 4);
    const bool in0 = act && gx_in && (gy0 >= 0) && (gy0 < HH);
    const bool in1 = act && gx_in && (gy1 >= 0) && (gy1 < HH);
    const int goff0 = in0 ? (gy0 * WW + gx) : 0;
    const int goff1 = in1 ? (gy1 * WW + gx) : 0;
    const bool is_int = act && (r0 >= HALO_Y) && (r1 < HALO_Y + TILE_H) &&
                        (x >= HALO_X) && (x < HALO_X + TILE_W);
    const float am = act ? 1.f : 0.f;
    float ca[4], cm[4], cb[4], h0[5], h1[5];
    {
        float4 a = *reinterpret_cast<const float4*>(&pv[r0 * CVW + x]);
        float4 m = *reinterpret_cast<const float4*>(&pv[r1 * CVW + x]);
        float4 d = *reinterpret_cast<const float4*>(&pv[(r1 + 1) * CVW + x]);
        ca[0] = a.x * am; ca[1] = a.y * am; ca[2] = a.z * am; ca[3] = a.w * am;
        cm[0] = m.x * am; cm[1] = m.y * am; cm[2] = m.z * am; cm[3] = m.w * am;
        cb[0] = d.x * am; cb[1] = d.y * am; cb[2] = d.z * am; cb[3] = d.w * am;
        float4 u = *reinterpret_cast<const float4*>(&ph[r0 * CHW + x]);
        float  u4 = ph[r0 * CHW + x + 4];
        float4 w = *reinterpret_cast<const float4*>(&ph[r1 * CHW + x]);
        float  w4 = ph[r1 * CHW + x + 4];
        h0[0] = u.x * am; h0[1] = u.y * am; h0[2] = u.z * am; h0[3] = u.w * am; h0[4] = u4 * am;
        h1[0] = w.x * am; h1[1] = w.y * am; h1[2] = w.z * am; h1[3] = w.w * am; h1[4] = w4 * am;
    }
    float v0[4] = {0.f, 0.f, 0.f, 0.f}, v1[4] = {0.f, 0.f, 0.f, 0.f};
    if (in0) {
        float4 tv = *reinterpret_cast<const float4*>(srcb + goff0);
        if (ADD_SHIFT) { tv.x += shift; tv.y += shift; tv.z += shift; tv.w += shift; }
        v0[0] = tv.x; v0[1] = tv.y; v0[2] = tv.z; v0[3] = tv.w;
    }
    if (in1) {
        float4 tv = *reinterpret_cast<const float4*>(srcb + goff1);
        if (ADD_SHIFT) { tv.x += shift; tv.y += shift; tv.z += shift; tv.w += shift; }
        v1[0] = tv.x; v1[1] = tv.y; v1[2] = tv.z; v1[3] = tv.w;
    }
    for (int i = tid; i < S_LDS; i += NTF) {
        sb[0][i] = 0.f; sb[0][(RH + 1) * S_LDS + i] = 0.f;
        sb[1][i] = 0.f; sb[1][(RH + 1) * S_LDS + i] = 0.f;
    }
    if (tid == 0) {
        float4 z{0.f, 0.f, 0.f, 0.f};
        *reinterpret_cast<float4*>(&sb[0][EDGE_OFF]) = z;
        *reinterpret_cast<float4*>(&sb[1][EDGE_OFF]) = z;
        *reinterpret_cast<float4*>(&sb[0][EDGE_OFF + 577 * 4]) = z;
        *reinterpret_cast<float4*>(&sb[1][EDGE_OFF + 577 * 4]) = z;
    }
    *reinterpret_cast<float4*>(&sb[0][roff0]) = float4{v0[0], v0[1], v0[2], v0[3]};
    *reinterpret_cast<float4*>(&sb[0][roff1]) = float4{v1[0], v1[1], v1[2], v1[3]};
    *reinterpret_cast<float4*>(&sb[0][e_w])   = float4{v0[0], v1[0], v0[3], v1[3]};
    __syncthreads();
    int cur = 0;
    for (int it = 0; it < T_FUSE; ++it) {
        const float* s = sb[cur];
        float2 lfp = *reinterpret_cast<const float2*>(&s[e_lf]);
        float2 rtp = *reinterpret_cast<const float2*>(&s[e_rt]);
        float4 up = *reinterpret_cast<const float4*>(&s[roff0 - S_LDS]);
        float4 dn = *reinterpret_cast<const float4*>(&s[roff1 + S_LDS]);
        float n0[4], n1[4];
        n0[0] = v0[0] - ca[0] * (v0[0] - up.x) + cm[0] * (v1[0] - v0[0])
                      - h0[0] * (v0[0] - lfp.x) + h0[1] * (v0[1] - v0[0]);
        n0[1] = v0[1] - ca[1] * (v0[1] - up.y) + cm[1] * (v1[1] - v0[1])
                      - h0[1] * (v0[1] - v0[0]) + h0[2] * (v0[2] - v0[1]);
        n0[2] = v0[2] - ca[2] * (v0[2] - up.z) + cm[2] * (v1[2] - v0[2])
                      - h0[2] * (v0[2] - v0[1]) + h0[3] * (v0[3] - v0[2]);
        n0[3] = v0[3] - ca[3] * (v0[3] - up.w) + cm[3] * (v1[3] - v0[3])
                      - h0[3] * (v0[3] - v0[2]) + h0[4] * (rtp.x - v0[3]);
        n1[0] = v1[0] - cm[0] * (v1[0] - v0[0]) + cb[0] * (dn.x - v1[0])
                      - h1[0] * (v1[0] - lfp.y) + h1[1] * (v1[1] - v1[0]);
        n1[1] = v1[1] - cm[1] * (v1[1] - v0[1]) + cb[1] * (dn.y - v1[1])
                      - h1[1] * (v1[1] - v1[0]) + h1[2] * (v1[2] - v1[1]);
        n1[2] = v1[2] - cm[2] * (v1[2] - v0[2]) + cb[2] * (dn.z - v1[2])
                      - h1[2] * (v1[2] - v1[1]) + h1[3] * (v1[3] - v1[2]);
        n1[3] = v1[3] - cm[3] * (v1[3] - v0[3]) + cb[3] * (dn.w - v1[3])
                      - h1[3] * (v1[3] - v1[2]) + h1[4] * (rtp.y - v1[3]);
        int nxt = cur ^ 1;
        float* d = sb[nxt];
        *reinterpret_cast<float4*>(&d[roff0]) = float4{n0[0], n0[1], n0[2], n0[3]};
        *reinterpret_cast<float4*>(&d[roff1]) = float4{n1[0], n1[1], n1[2], n1[3]};
        *reinterpret_cast<float4*>(&d[e_w])   = float4{n0[0], n1[0], n0[3], n1[3]};
        v0[0] = n0[0]; v0[1] = n0[1]; v0[2] = n0[2]; v0[3] = n0[3];
        v1[0] = n1[0]; v1[1] = n1[1]; v1[2] = n1[2]; v1[3] = n1[3];
        cur = nxt;
        __syncthreads();
    }
    float* dstb = dst + b * IMG;
    if (is_int) {
        float4 o0{v0[0], v0[1], v0[2], v0[3]};
        float4 o1{v1[0], v1[1], v1[2], v1[3]};
        if (SUB_SHIFT) {
            o0.x -= shift; o0.y -= shift; o0.z -= shift; o0.w -= shift;
            o1.x -= shift; o1.y -= shift; o1.z -= shift; o1.w -= shift;
        }
        *reinterpret_cast<float4*>(dstb + goff0) = o0;
        *reinterpret_cast<float4*>(dstb + goff1) = o1;
    }
}

// -------- fallback (round-2 verified, inline gather, 256 threads) --------
template <bool ADD_SHIFT, bool SUB_SHIFT>
__global__ __launch_bounds__(256, 1) void step_fused(
    const float* __restrict__ src, float* __restrict__ dst,
    const float* __restrict__ cv_g, const float* __restrict__ ch_g,
    const unsigned* __restrict__ key) {
    __shared__ float sb[2][SSZ];
    const int blk = blockIdx.x;
    const int b = blk >> 7, t = blk & 127;
    const int y0 = (t >> 3) * TILE_H, x0 = (t & 7) * TILE_W;
    const float* cvb = cv_g + b * CV_PER_B;
    const float* chb = ch_g + b * CH_PER_B;
    const float* srcb = src + b * IMG;
    float* dstb = dst + b * IMG;
    float shift = 0.f;
    if (ADD_SHIFT || SUB_SHIFT) shift = (kinv(*key) <= DEPS_) ? DEPS_ : 0.f;
    const int tid = threadIdx.x;
    float v[QPT_F][4], cu[QPT_F][4], cd[QPT_F][4], chq[QPT_F][5];
    int roff[QPT_F], rr[QPT_F], xx[QPT_F];
    bool act[QPT_F];
#pragma unroll
    for (int q = 0; q < QPT_F; ++q) {
        int qi = tid + q * 256;
        act[q] = qi < NQUAD;
        int qc = act[q] ? qi : 0;
        int r = qc / NQ_ROW;
        int x = (qc - r * NQ_ROW) * 4;
        rr[q] = r; xx[q] = x;
        roff[q] = (r + 1) * RW + x;
        int gy = y0 - HALO_Y + r, gx = x0 - HALO_X + x;
        bool gy_in = (gy >= 0) && (gy < HH);
#pragma unroll
        for (int j = 0; j < 4; ++j) {
            int gxx = gx + j;
            bool gx_in = (gxx >= 0) && (gxx < WW);
            bool vin = act[q] && gy_in && gx_in;
            float val = vin ? srcb[gy * WW + gxx] : 0.f;
            if (ADD_SHIFT) val += shift;
            v[q][j] = vin ? val : 0.f;
            bool up_ok = act[q] && (r >= 1) && (gy >= 1) && (gy < HH) && gx_in;
            cu[q][j] = up_ok ? LAM * cvb[(gy - 1) * WW + gxx] : 0.f;
            bool dn_ok = act[q] && (r <= RH - 2) && (gy >= 0) && (gy < HH - 1) && gx_in;
            cd[q][j] = dn_ok ? LAM * cvb[gy * WW + gxx] : 0.f;
        }
#pragma unroll
        for (int jj = 0; jj < 5; ++jj) {
            int xe = x + jj, gxe = gx + jj;
            bool ok = act[q] && (xe >= 1) && (xe <= RW - 1) && gy_in &&
                      (gxe >= 1) && (gxe < WW);
            chq[q][jj] = ok ? LAM * chb[gy * (WW - 1) + (gxe - 1)] : 0.f;
        }
    }
    for (int i = tid; i < RW; i += 256) {
        sb[0][i] = 0.f; sb[0][(RH + 1) * RW + i] = 0.f;
        sb[1][i] = 0.f; sb[1][(RH + 1) * RW + i] = 0.f;
    }
#pragma unroll
    for (int q = 0; q < QPT_F; ++q)
        if (act[q])
            *reinterpret_cast<float4*>(&sb[0][roff[q]]) =
                float4{v[q][0], v[q][1], v[q][2], v[q][3]};
    __syncthreads();
    int cur = 0;
    for (int it = 0; it < T_FUSE; ++it) {
        float nv[QPT_F][4];
#pragma unroll
        for (int q = 0; q < QPT_F; ++q) {
            const float* s = sb[cur];
            float4 up = *reinterpret_cast<const float4*>(&s[roff[q] - RW]);
            float4 dn = *reinterpret_cast<const float4*>(&s[roff[q] + RW]);
            float lf = s[roff[q] - 1];
            float rt = s[roff[q] + 4];
            float c0 = v[q][0], c1 = v[q][1], c2 = v[q][2], c3 = v[q][3];
            nv[q][0] = c0 - cu[q][0] * (c0 - up.x) + cd[q][0] * (dn.x - c0)
                          - chq[q][0] * (c0 - lf) + chq[q][1] * (c1 - c0);
            nv[q][1] = c1 - cu[q][1] * (c1 - up.y) + cd[q][1] * (dn.y - c1)
                          - chq[q][1] * (c1 - c0) + chq[q][2] * (c2 - c1);
            nv[q][2] = c2 - cu[q][2] * (c2 - up.z) + cd[q][2] * (dn.z - c2)
                          - chq[q][2] * (c2 - c1) + chq[q][3] * (c3 - c2);
            nv[q][3] = c3 - cu[q][3] * (c3 - up.w) + cd[q][3] * (dn.w - c3)
                          - chq[q][3] * (c3 - c2) + chq[q][4] * (rt - c3);
        }
        int nxt = cur ^ 1;
#pragma unroll
        for (int q = 0; q < QPT_F; ++q) {
            if (act[q])
                *reinterpret_cast<float4*>(&sb[nxt][roff[q]]) =
                    float4{nv[q][0], nv[q][1], nv[q][2], nv[q][3]};
            v[q][0] = nv[q][0]; v[q][1] = nv[q][1];
            v[q][2] = nv[q][2]; v[q][3] = nv[q][3];
        }
        cur = nxt;
        __syncthreads();
    }
#pragma unroll
    for (int q = 0; q < QPT_F; ++q) {
        if (!act[q]) continue;
        int r = rr[q], x = xx[q];
        if (r >= HALO_Y && r < HALO_Y + TILE_H && x >= HALO_X && x < HALO_X + TILE_W) {
            int gy = y0 - HALO_Y + r, gx = x0 - HALO_X + x;
            float4 o{v[q][0], v[q][1], v[q][2], v[q][3]};
            if (SUB_SHIFT) { o.x -= shift; o.y -= shift; o.z -= shift; o.w -= shift; }
            *reinterpret_cast<float4*>(dstb + gy * WW + gx) = o;
        }
    }
}

extern "C" void kernel_launch(void* const* d_in, const int* in_sizes, int n_in,
                              void* d_out, int out_size, void* d_ws, size_t ws_size,
                              hipStream_t stream) {
    const float* guide   = (const float*)d_in[0];
    const float* initial = (const float*)d_in[1];
    float* out    = (float*)d_out;
    float* out_y  = out;
    float* out_cv = out + N_DEPTH;
    float* out_ch = out + N_DEPTH + N_CV;

    unsigned* key = (unsigned*)d_ws;
    float* wsf    = (float*)d_ws;
    float* bufA   = wsf + 64;
    float* bufB   = bufA + N_DEPTH;
    float* blob   = bufB + N_DEPTH;
    unsigned* flags = (unsigned*)(blob + 256 * BLOB_BLK);

    const size_t need = (size_t)(64 + 2 * N_DEPTH + 256 * BLOB_BLK + 256) * 4;
    const bool fast = ws_size >= need;

    hipLaunchKernelGGL(init_key_kernel, dim3(1), dim3(256), 0, stream, key, flags);
    hipLaunchKernelGGL(min_kernel, dim3(256), dim3(256), 0, stream, initial, key);

    int nco = N_CV + N_CH;
    hipLaunchKernelGGL(coeff_kernel, dim3((nco + 255) / 256), dim3(256), 0, stream,
                       guide, out_cv, out_ch);

    if (fast) {
        hipLaunchKernelGGL(prep_planes, dim3(256), dim3(256), 0, stream,
                           out_cv, out_ch, blob);
        const float* a0 = initial;
        float* a1 = out_y;
        float* a2 = bufA;
        float* a3 = bufB;
        const float* a4 = blob;
        const unsigned* a5 = key;
        unsigned* a6 = flags;
        void* kargs[] = {&a0, &a1, &a2, &a3, &a4, &a5, &a6};
        hipError_t ce = hipLaunchCooperativeKernel(
            (const void*)diffuse_persist, dim3(256), dim3(NTF), kargs, 0, stream);
        if (ce == hipSuccess) return;
        // cooperative unsupported -> verified R7 relaunch path
        float* bufs[2] = {bufA, bufB};
        for (int k = 0; k < NSS; ++k) {
            const float* src = (k == 0) ? initial : bufs[(k + 1) & 1];
            float*       dst = (k == NSS - 1) ? out_y : bufs[k & 1];
            if (k == 0)
                hipLaunchKernelGGL((step_fast<true, false>), dim3(256), dim3(NTF), 0,
                                   stream, src, dst, blob, key);
            else if (k == NSS - 1)
                hipLaunchKernelGGL((step_fast<false, true>), dim3(256), dim3(NTF), 0,
                                   stream, src, dst, blob, key);
            else
                hipLaunchKernelGGL((step_fast<false, false>), dim3(256), dim3(NTF), 0,
                                   stream, src, dst, blob, key);
        }
        return;
    }

    float* bufs[2] = {bufA, bufB};
    for (int k = 0; k < NSS; ++k) {
        const float* src = (k == 0) ? initial : bufs[(k + 1) & 1];
        float*       dst = (k == NSS - 1) ? out_y : bufs[k & 1];
        if (k == 0)
            hipLaunchKernelGGL((step_fused<true, false>), dim3(256), dim3(256), 0,
                               stream, src, dst, out_cv, out_ch, key);
        else if (k == NSS - 1)
            hipLaunchKernelGGL((step_fused<false, true>), dim3(256), dim3(256), 0,
                               stream, src, dst, out_cv, out_ch, key);
        else
            hipLaunchKernelGGL((step_fused<false, false>), dim3(256), dim3(256), 0,
                               stream, src, dst, out_cv, out_ch, key);
    }
}

// Round 8
// 486.615 us; speedup vs baseline: 6.0399x; 6.0399x over previous
//
#include <hip/hip_runtime.h>

// Perona-Malik diffusion, 500 iters. Round-12: persistent kernel v2.
// R11 post-mortem: agent-scope FENCES were the killer (each block, each
// superstep: buffer_wbl2 on release + buffer_inv on acquire; 32 blk/XCD x 50
// supersteps = 1600 full-L2 writebacks+invalidates per XCD -> 57us/superstep,
// VALUBusy 3.9%). v2 removes ALL fences: interior writes and halo reads use
// per-access coherent ops (__hip_atomic_ 8B, relaxed, AGENT scope -> sc-bit
// global ops that bypass L1/L2 to the device coherence point). Ordering:
// each thread s_waitcnt vmcnt(0) before the end-of-superstep barrier, then
// tid0 posts the flag (relaxed) -- data reaches the coherence point before
// the flag does; readers spin (relaxed) + barrier + compiler barrier, then
// coherent halo loads that cannot hit stale cache. L2 stays clean -> nothing
// to write back, nothing to invalidate. Same data-flow, same FMA order ->
// bit-identical. Fallback chain: coop-launch failure -> R7 relaunch (495us).

#define HH 512
#define WW 512
#define NB 2
static constexpr float LAM   = 0.24f;
static constexpr float KCOND = 0.03f;
static constexpr float DEPS_ = 0.1f;
static constexpr int IMG      = HH * WW;
static constexpr int N_DEPTH  = NB * IMG;
static constexpr int CV_PER_B = (HH - 1) * WW;
static constexpr int CH_PER_B = HH * (WW - 1);
static constexpr int N_CV     = NB * CV_PER_B;
static constexpr int N_CH     = NB * CH_PER_B;

static constexpr int T_FUSE = 10, NSS = 50;       // 50 x 10 = 500
static constexpr int TILE_W = 64, TILE_H = 32;
static constexpr int HALO_X = 12, HALO_Y = 10;
static constexpr int RW = TILE_W + 2 * HALO_X;    // 88
static constexpr int RH = TILE_H + 2 * HALO_Y;    // 52
static constexpr int NQ_ROW = RW / 4;             // 22
static constexpr int NQUAD  = NQ_ROW * RH;        // 1144 (fallback)
static constexpr int SSZ    = (RH + 2) * RW;      // fallback layout (4752)

// fast path: 4x2 units, one per thread (R7 geometry, 495us verified)
static constexpr int NU_ROW = RW / 4;              // 22 units per row-pair
static constexpr int NU_COL = RH / 2;              // 26 row-pairs
static constexpr int NUNIT  = NU_ROW * NU_COL;     // 572
static constexpr int NTF    = 576;                 // 9 waves

// fast-path LDS layout (floats), per ping-pong buffer (R7):
static constexpr int S_LDS    = 92;
static constexpr int ROWS_SZ  = (RH + 2) * S_LDS;       // 4968
static constexpr int TRASH_OFF = ROWS_SZ;               // 4968
static constexpr int EDGE_OFF = ROWS_SZ + S_LDS;        // 5060 (16B aligned)
static constexpr int EDGE_ENT = 580;                    // entries 0..577 used
static constexpr int BUF_SZ   = EDGE_OFF + EDGE_ENT * 4; // 7380

// coefficient planes (per block), R7 layout
static constexpr int CVW = RW;                     // 88
static constexpr int CV_SZ = (RH + 1) * CVW;       // 4664
static constexpr int CHW = RW + 8;                 // 96
static constexpr int CH_SZ = RH * CHW;             // 4992
static constexpr int BLOB_BLK = CV_SZ + CH_SZ;     // 9656 floats/block

// fallback path (round-2 verified): 256 threads, 5 quads/thread
static constexpr int QPT_F = 5;

// ---- monotone float<->uint key for atomic min ----
__device__ __forceinline__ unsigned fkey(float f) {
    unsigned u = __float_as_uint(f);
    return (u & 0x80000000u) ? ~u : (u | 0x80000000u);
}
__device__ __forceinline__ float kinv(unsigned k) {
    return __uint_as_float((k & 0x80000000u) ? (k & 0x7fffffffu) : ~k);
}

// ---- per-access coherent 8B load/store (agent scope, relaxed) ----
__device__ __forceinline__ float2 cohload8(const float* p) {
    unsigned long long u = __hip_atomic_load(
        reinterpret_cast<const unsigned long long*>(p),
        __ATOMIC_RELAXED, __HIP_MEMORY_SCOPE_AGENT);
    union { unsigned long long u; float2 f; } c; c.u = u;
    return c.f;
}
__device__ __forceinline__ void cohstore8(float* p, float a, float b) {
    union { unsigned long long u; float f[2]; } c;
    c.f[0] = a; c.f[1] = b;
    __hip_atomic_store(reinterpret_cast<unsigned long long*>(p), c.u,
                       __ATOMIC_RELAXED, __HIP_MEMORY_SCOPE_AGENT);
}

__global__ void init_key_kernel(unsigned* key, unsigned* flags) {
    if (threadIdx.x == 0) *key = 0xFFFFFFFFu;
    flags[threadIdx.x] = 0u;   // 256 threads, one flag per persistent block
}

__global__ void min_kernel(const float* __restrict__ x, unsigned* key) {
    float m = 3.4e38f;
    for (int idx = blockIdx.x * blockDim.x + threadIdx.x; idx < N_DEPTH;
         idx += gridDim.x * blockDim.x)
        m = fminf(m, x[idx]);
    for (int off = 32; off > 0; off >>= 1) m = fminf(m, __shfl_down(m, off, 64));
    __shared__ float sm[4];
    int lane = threadIdx.x & 63, wv = threadIdx.x >> 6;
    if (lane == 0) sm[wv] = m;
    __syncthreads();
    if (threadIdx.x == 0) {
        float mm = fminf(fminf(sm[0], sm[1]), fminf(sm[2], sm[3]));
        atomicMin(key, fkey(mm));
    }
}

__global__ void coeff_kernel(const float* __restrict__ g, float* __restrict__ cv,
                             float* __restrict__ chh) {
    int idx = blockIdx.x * blockDim.x + threadIdx.x;
    constexpr float kk = KCOND * KCOND;
    if (idx < N_CV) {
        int b = idx / CV_PER_B;
        int r = idx - b * CV_PER_B;
        int i = r >> 9, j = r & (WW - 1);
        const float* gb = g + b * 3 * IMG + i * WW + j;
        float s = 0.f;
#pragma unroll
        for (int c = 0; c < 3; ++c) s += fabsf(gb[c * IMG + WW] - gb[c * IMG]);
        float m = s / 3.0f;
        cv[idx] = 1.0f / (1.0f + (m * m) / kk);
    } else if (idx < N_CV + N_CH) {
        int t = idx - N_CV;
        int b = t / CH_PER_B;
        int r = t - b * CH_PER_B;
        int i = r / (WW - 1);
        int j = r - i * (WW - 1);
        const float* gb = g + b * 3 * IMG + i * WW + j;
        float s = 0.f;
#pragma unroll
        for (int c = 0; c < 3; ++c) s += fabsf(gb[c * IMG + 1] - gb[c * IMG]);
        float m = s / 3.0f;
        chh[t] = 1.0f / (1.0f + (m * m) / kk);
    }
}

// One-time: bake predicated L*cv / L*ch into dense per-block planes.
__global__ __launch_bounds__(256) void prep_planes(const float* __restrict__ cv_g,
                                                   const float* __restrict__ ch_g,
                                                   float* __restrict__ blob) {
    const int blk = blockIdx.x;
    const int b   = blk >> 7, t = blk & 127;
    const int y0  = (t >> 3) * TILE_H;
    const int x0  = (t & 7) * TILE_W;
    const float* cvb = cv_g + b * CV_PER_B;
    const float* chb = ch_g + b * CH_PER_B;
    float* pv = blob + blk * BLOB_BLK;
    float* ph = pv + CV_SZ;
    for (int i = threadIdx.x; i < CV_SZ; i += 256) {
        int rr = i / CVW, x = i - rr * CVW;
        int gy = y0 - HALO_Y + rr, gx = x0 - HALO_X + x;
        bool ok = (rr >= 1) && (rr <= RH - 1) && (gy >= 1) && (gy <= HH - 1) &&
                  (gx >= 0) && (gx < WW);
        pv[i] = ok ? LAM * cvb[(gy - 1) * WW + gx] : 0.f;
    }
    for (int i = threadIdx.x; i < CH_SZ; i += 256) {
        int rr = i / CHW, xe = i - rr * CHW;
        int gy = y0 - HALO_Y + rr, gxe = x0 - HALO_X + xe;
        bool ok = (xe >= 1) && (xe <= RW - 1) && (gy >= 0) && (gy < HH) &&
                  (gxe >= 1) && (gxe < WW);
        ph[i] = ok ? LAM * chb[gy * (WW - 1) + (gxe - 1)] : 0.f;
    }
}

// ================= persistent cooperative kernel (v2: no fences) =========
__global__ __launch_bounds__(NTF, 1) void diffuse_persist(
    const float* __restrict__ initial, float* __restrict__ out_y,
    float* __restrict__ bufA, float* __restrict__ bufB,
    const float* __restrict__ blob, const unsigned* __restrict__ key,
    unsigned* __restrict__ flags) {
    __shared__ float sb[2][BUF_SZ];
    const int blk = blockIdx.x;
    const int b   = blk >> 7, t = blk & 127;
    const int ty  = t >> 3, tx = t & 7;
    const int y0  = ty * TILE_H;
    const int x0  = tx * TILE_W;
    const float* pv = blob + blk * BLOB_BLK;
    const float* ph = pv + CV_SZ;
    const float shift = (kinv(*key) <= DEPS_) ? DEPS_ : 0.f;
    const int tid = threadIdx.x;

    // ---- unit geometry: 4 wide x 2 tall (R7) ----
    const bool act = tid < NUNIT;
    const int  uc  = act ? tid : 0;
    const int  pr  = uc / NU_ROW;
    const int  px  = uc - pr * NU_ROW;
    const int  x   = px * 4;
    const int  r0  = 2 * pr, r1 = r0 + 1;
    int roff0 = (r0 + 1) * S_LDS + x;
    int roff1 = roff0 + S_LDS;
    if (!act) { roff0 = TRASH_OFF + (tid & 3) * 8; roff1 = roff0 + 4; }
    const int e_w  = EDGE_OFF + (tid + 1) * 4;
    const int e_lf = EDGE_OFF + tid * 4 + 2;
    const int e_rt = EDGE_OFF + (tid + 2) * 4;

    const int gy0 = y0 - HALO_Y + r0, gy1 = gy0 + 1;
    const int gx  = x0 - HALO_X + x;
    const bool gx_in = (gx >= 0) && (gx <= WW - 4);
    const bool in0 = act && gx_in && (gy0 >= 0) && (gy0 < HH);
    const bool in1 = act && gx_in && (gy1 >= 0) && (gy1 < HH);
    const int goff0 = in0 ? (gy0 * WW + gx) : 0;
    const int goff1 = in1 ? (gy1 * WW + gx) : 0;
    const bool is_int = act && (r0 >= HALO_Y) && (r1 < HALO_Y + TILE_H) &&
                        (x >= HALO_X) && (x < HALO_X + TILE_W);

    // ---- coefficients ONCE (baked, predicated) ----
    const float am = act ? 1.f : 0.f;
    float ca[4], cm[4], cb[4], h0[5], h1[5];
    {
        float4 a = *reinterpret_cast<const float4*>(&pv[r0 * CVW + x]);
        float4 m = *reinterpret_cast<const float4*>(&pv[r1 * CVW + x]);
        float4 d = *reinterpret_cast<const float4*>(&pv[(r1 + 1) * CVW + x]);
        ca[0] = a.x * am; ca[1] = a.y * am; ca[2] = a.z * am; ca[3] = a.w * am;
        cm[0] = m.x * am; cm[1] = m.y * am; cm[2] = m.z * am; cm[3] = m.w * am;
        cb[0] = d.x * am; cb[1] = d.y * am; cb[2] = d.z * am; cb[3] = d.w * am;
        float4 u = *reinterpret_cast<const float4*>(&ph[r0 * CHW + x]);
        float  u4 = ph[r0 * CHW + x + 4];
        float4 w = *reinterpret_cast<const float4*>(&ph[r1 * CHW + x]);
        float  w4 = ph[r1 * CHW + x + 4];
        h0[0] = u.x * am; h0[1] = u.y * am; h0[2] = u.z * am; h0[3] = u.w * am; h0[4] = u4 * am;
        h1[0] = w.x * am; h1[1] = w.y * am; h1[2] = w.z * am; h1[3] = w.w * am; h1[4] = w4 * am;
    }

    // ---- neighbor flag index (tid<8 -> one of 8 neighbors) ----
    int nbr = -1;
    if (tid < 8) {
        int d  = tid + (tid >= 4 ? 1 : 0);      // 0..8 skipping center(4)
        int dy = d / 3 - 1, dx = d % 3 - 1;
        int ny = ty + dy, nx = tx + dx;
        if (ny >= 0 && ny < 16 && nx >= 0 && nx < 8)
            nbr = (b << 7) + (ny << 3) + nx;
    }

    // ---- superstep-0 full load (+shift) ----
    float v0[4] = {0.f, 0.f, 0.f, 0.f}, v1[4] = {0.f, 0.f, 0.f, 0.f};
    const float* ib = initial + b * IMG;
    if (in0) {
        float4 tv = *reinterpret_cast<const float4*>(ib + goff0);
        v0[0] = tv.x + shift; v0[1] = tv.y + shift; v0[2] = tv.z + shift; v0[3] = tv.w + shift;
    }
    if (in1) {
        float4 tv = *reinterpret_cast<const float4*>(ib + goff1);
        v1[0] = tv.x + shift; v1[1] = tv.y + shift; v1[2] = tv.z + shift; v1[3] = tv.w + shift;
    }

    // guard rows + edge sentinels (once; they stay valid across supersteps)
    for (int i = tid; i < S_LDS; i += NTF) {
        sb[0][i] = 0.f; sb[0][(RH + 1) * S_LDS + i] = 0.f;
        sb[1][i] = 0.f; sb[1][(RH + 1) * S_LDS + i] = 0.f;
    }
    if (tid == 0) {
        float4 z{0.f, 0.f, 0.f, 0.f};
        *reinterpret_cast<float4*>(&sb[0][EDGE_OFF]) = z;
        *reinterpret_cast<float4*>(&sb[1][EDGE_OFF]) = z;
        *reinterpret_cast<float4*>(&sb[0][EDGE_OFF + 577 * 4]) = z;
        *reinterpret_cast<float4*>(&sb[1][EDGE_OFF + 577 * 4]) = z;
    }
    *reinterpret_cast<float4*>(&sb[0][roff0]) = float4{v0[0], v0[1], v0[2], v0[3]};
    *reinterpret_cast<float4*>(&sb[0][roff1]) = float4{v1[0], v1[1], v1[2], v1[3]};
    *reinterpret_cast<float4*>(&sb[0][e_w])   = float4{v0[0], v1[0], v0[3], v1[3]};
    __syncthreads();

    for (int k = 0; k < NSS; ++k) {
        if (k > 0) {
            // wait: 8 neighbors must have COMPLETED superstep k-1
            if (nbr >= 0) {
                while (__hip_atomic_load(&flags[nbr], __ATOMIC_RELAXED,
                                         __HIP_MEMORY_SCOPE_AGENT) < (unsigned)k)
                    __builtin_amdgcn_s_sleep(1);
            }
            __syncthreads();
            asm volatile("" ::: "memory");   // no compiler reordering past spin
            // halo units reload via coherent loads; interior persists
            const float* srcb = ((k & 1) ? bufA : bufB) + b * IMG;
            if (act && !is_int) {
                float2 a0{0.f, 0.f}, b0{0.f, 0.f}, a1{0.f, 0.f}, b1{0.f, 0.f};
                if (in0) { a0 = cohload8(srcb + goff0); b0 = cohload8(srcb + goff0 + 2); }
                if (in1) { a1 = cohload8(srcb + goff1); b1 = cohload8(srcb + goff1 + 2); }
                v0[0] = a0.x; v0[1] = a0.y; v0[2] = b0.x; v0[3] = b0.y;
                v1[0] = a1.x; v1[1] = a1.y; v1[2] = b1.x; v1[3] = b1.y;
                *reinterpret_cast<float4*>(&sb[0][roff0]) =
                    float4{v0[0], v0[1], v0[2], v0[3]};
                *reinterpret_cast<float4*>(&sb[0][roff1]) =
                    float4{v1[0], v1[1], v1[2], v1[3]};
                *reinterpret_cast<float4*>(&sb[0][e_w]) =
                    float4{v0[0], v1[0], v0[3], v1[3]};
            }
            __syncthreads();
        }

        int cur = 0;
        for (int it = 0; it < T_FUSE; ++it) {
            const float* s = sb[cur];
            float2 lfp = *reinterpret_cast<const float2*>(&s[e_lf]);
            float2 rtp = *reinterpret_cast<const float2*>(&s[e_rt]);
            float4 up = *reinterpret_cast<const float4*>(&s[roff0 - S_LDS]);
            float4 dn = *reinterpret_cast<const float4*>(&s[roff1 + S_LDS]);

            float n0[4], n1[4];
            n0[0] = v0[0] - ca[0] * (v0[0] - up.x) + cm[0] * (v1[0] - v0[0])
                          - h0[0] * (v0[0] - lfp.x) + h0[1] * (v0[1] - v0[0]);
            n0[1] = v0[1] - ca[1] * (v0[1] - up.y) + cm[1] * (v1[1] - v0[1])
                          - h0[1] * (v0[1] - v0[0]) + h0[2] * (v0[2] - v0[1]);
            n0[2] = v0[2] - ca[2] * (v0[2] - up.z) + cm[2] * (v1[2] - v0[2])
                          - h0[2] * (v0[2] - v0[1]) + h0[3] * (v0[3] - v0[2]);
            n0[3] = v0[3] - ca[3] * (v0[3] - up.w) + cm[3] * (v1[3] - v0[3])
                          - h0[3] * (v0[3] - v0[2]) + h0[4] * (rtp.x - v0[3]);
            n1[0] = v1[0] - cm[0] * (v1[0] - v0[0]) + cb[0] * (dn.x - v1[0])
                          - h1[0] * (v1[0] - lfp.y) + h1[1] * (v1[1] - v1[0]);
            n1[1] = v1[1] - cm[1] * (v1[1] - v0[1]) + cb[1] * (dn.y - v1[1])
                          - h1[1] * (v1[1] - v1[0]) + h1[2] * (v1[2] - v1[1]);
            n1[2] = v1[2] - cm[2] * (v1[2] - v0[2]) + cb[2] * (dn.z - v1[2])
                          - h1[2] * (v1[2] - v1[1]) + h1[3] * (v1[3] - v1[2]);
            n1[3] = v1[3] - cm[3] * (v1[3] - v0[3]) + cb[3] * (dn.w - v1[3])
                          - h1[3] * (v1[3] - v1[2]) + h1[4] * (rtp.y - v1[3]);

            int nxt = cur ^ 1;
            float* d = sb[nxt];
            *reinterpret_cast<float4*>(&d[roff0]) = float4{n0[0], n0[1], n0[2], n0[3]};
            *reinterpret_cast<float4*>(&d[roff1]) = float4{n1[0], n1[1], n1[2], n1[3]};
            *reinterpret_cast<float4*>(&d[e_w])   = float4{n0[0], n1[0], n0[3], n1[3]};
            v0[0] = n0[0]; v0[1] = n0[1]; v0[2] = n0[2]; v0[3] = n0[3];
            v1[0] = n1[0]; v1[1] = n1[1]; v1[2] = n1[2]; v1[3] = n1[3];
            cur = nxt;
            __syncthreads();
        }
        // T_FUSE even -> final values live in sb[0]; LDS stays valid for k+1.

        if (k == NSS - 1) {
            float* dstb = out_y + b * IMG;
            if (is_int) {
                float4 o0{v0[0] - shift, v0[1] - shift, v0[2] - shift, v0[3] - shift};
                float4 o1{v1[0] - shift, v1[1] - shift, v1[2] - shift, v1[3] - shift};
                *reinterpret_cast<float4*>(dstb + goff0) = o0;
                *reinterpret_cast<float4*>(dstb + goff1) = o1;
            }
        } else {
            float* dstb = ((k & 1) ? bufB : bufA) + b * IMG;
            if (is_int) {
                cohstore8(dstb + goff0,     v0[0], v0[1]);
                cohstore8(dstb + goff0 + 2, v0[2], v0[3]);
                cohstore8(dstb + goff1,     v1[0], v1[1]);
                cohstore8(dstb + goff1 + 2, v1[2], v1[3]);
            }
            // every thread drains ITS OWN coherent stores to the coherence
            // point, then the barrier orders all of them before the flag.
            asm volatile("s_waitcnt vmcnt(0)" ::: "memory");
            __syncthreads();
            if (tid == 0)
                __hip_atomic_store(&flags[blk], (unsigned)(k + 1),
                                   __ATOMIC_RELAXED, __HIP_MEMORY_SCOPE_AGENT);
        }
    }
}

// ---------- R7 relaunch step kernel (fallback if cooperative fails) ----------
template <bool ADD_SHIFT, bool SUB_SHIFT>
__global__ __launch_bounds__(NTF, 1) void step_fast(
    const float* __restrict__ src, float* __restrict__ dst,
    const float* __restrict__ blob, const unsigned* __restrict__ key) {
    __shared__ float sb[2][BUF_SZ];
    const int blk = blockIdx.x;
    const int b   = blk >> 7, t = blk & 127;
    const int y0  = (t >> 3) * TILE_H;
    const int x0  = (t & 7) * TILE_W;
    const float* srcb = src + b * IMG;
    const float* pv   = blob + blk * BLOB_BLK;
    const float* ph   = pv + CV_SZ;
    float shift = 0.f;
    if (ADD_SHIFT || SUB_SHIFT) shift = (kinv(*key) <= DEPS_) ? DEPS_ : 0.f;
    const int tid = threadIdx.x;
    const bool act = tid < NUNIT;
    const int  uc  = act ? tid : 0;
    const int  pr  = uc / NU_ROW;
    const int  px  = uc - pr * NU_ROW;
    const int  x   = px * 4;
    const int  r0  = 2 * pr, r1 = r0 + 1;
    int roff0 = (r0 + 1) * S_LDS + x;
    int roff1 = roff0 + S_LDS;
    if (!act) { roff0 = TRASH_OFF + (tid & 3) * 8; roff1 = roff0 + 4; }
    const int e_w  = EDGE_OFF + (tid + 1) * 4;
    const int e_lf = EDGE_OFF + tid * 4 + 2;
    const int e_rt = EDGE_OFF + (tid + 2) * 4;
    const int gy0 = y0 - HALO_Y + r0, gy1 = gy0 + 1;
    const int gx  = x0 - HALO_X + x;
    const bool gx_in = (gx >= 0) && (gx <= WW - 4);
    const bool in0 = act && gx_in && (gy0 >= 0) && (gy0 < HH);
    const bool in1 = act && gx_in && (gy1 >= 0) && (gy1 < HH);
    const int goff0 = in0 ? (gy0 * WW + gx) : 0;
    const int goff1 = in1 ? (gy1 * WW + gx) : 0;
    const bool is_int = act && (r0 >= HALO_Y) && (r1 < HALO_Y + TILE_H) &&
                        (x >= HALO_X) && (x < HALO_X + TILE_W);
    const float am = act ? 1.f : 0.f;
    float ca[4], cm[4], cb[4], h0[5], h1[5];
    {
        float4 a = *reinterpret_cast<const float4*>(&pv[r0 * CVW + x]);
        float4 m = *reinterpret_cast<const float4*>(&pv[r1 * CVW + x]);
        float4 d = *reinterpret_cast<const float4*>(&pv[(r1 + 1) * CVW + x]);
        ca[0] = a.x * am; ca[1] = a.y * am; ca[2] = a.z * am; ca[3] = a.w * am;
        cm[0] = m.x * am; cm[1] = m.y * am; cm[2] = m.z * am; cm[3] = m.w * am;
        cb[0] = d.x * am; cb[1] = d.y * am; cb[2] = d.z * am; cb[3] = d.w * am;
        float4 u = *reinterpret_cast<const float4*>(&ph[r0 * CHW + x]);
        float  u4 = ph[r0 * CHW + x + 4];
        float4 w = *reinterpret_cast<const float4*>(&ph[r1 * CHW + x]);
        float  w4 = ph[r1 * CHW + x + 4];
        h0[0] = u.x * am; h0[1] = u.y * am; h0[2] = u.z * am; h0[3] = u.w * am; h0[4] = u4 * am;
        h1[0] = w.x * am; h1[1] = w.y * am; h1[2] = w.z * am; h1[3] = w.w * am; h1[4] = w4 * am;
    }
    float v0[4] = {0.f, 0.f, 0.f, 0.f}, v1[4] = {0.f, 0.f, 0.f, 0.f};
    if (in0) {
        float4 tv = *reinterpret_cast<const float4*>(srcb + goff0);
        if (ADD_SHIFT) { tv.x += shift; tv.y += shift; tv.z += shift; tv.w += shift; }
        v0[0] = tv.x; v0[1] = tv.y; v0[2] = tv.z; v0[3] = tv.w;
    }
    if (in1) {
        float4 tv = *reinterpret_cast<const float4*>(srcb + goff1);
        if (ADD_SHIFT) { tv.x += shift; tv.y += shift; tv.z += shift; tv.w += shift; }
        v1[0] = tv.x; v1[1] = tv.y; v1[2] = tv.z; v1[3] = tv.w;
    }
    for (int i = tid; i < S_LDS; i += NTF) {
        sb[0][i] = 0.f; sb[0][(RH + 1) * S_LDS + i] = 0.f;
        sb[1][i] = 0.f; sb[1][(RH + 1) * S_LDS + i] = 0.f;
    }
    if (tid == 0) {
        float4 z{0.f, 0.f, 0.f, 0.f};
        *reinterpret_cast<float4*>(&sb[0][EDGE_OFF]) = z;
        *reinterpret_cast<float4*>(&sb[1][EDGE_OFF]) = z;
        *reinterpret_cast<float4*>(&sb[0][EDGE_OFF + 577 * 4]) = z;
        *reinterpret_cast<float4*>(&sb[1][EDGE_OFF + 577 * 4]) = z;
    }
    *reinterpret_cast<float4*>(&sb[0][roff0]) = float4{v0[0], v0[1], v0[2], v0[3]};
    *reinterpret_cast<float4*>(&sb[0][roff1]) = float4{v1[0], v1[1], v1[2], v1[3]};
    *reinterpret_cast<float4*>(&sb[0][e_w])   = float4{v0[0], v1[0], v0[3], v1[3]};
    __syncthreads();
    int cur = 0;
    for (int it = 0; it < T_FUSE; ++it) {
        const float* s = sb[cur];
        float2 lfp = *reinterpret_cast<const float2*>(&s[e_lf]);
        float2 rtp = *reinterpret_cast<const float2*>(&s[e_rt]);
        float4 up = *reinterpret_cast<const float4*>(&s[roff0 - S_LDS]);
        float4 dn = *reinterpret_cast<const float4*>(&s[roff1 + S_LDS]);
        float n0[4], n1[4];
        n0[0] = v0[0] - ca[0] * (v0[0] - up.x) + cm[0] * (v1[0] - v0[0])
                      - h0[0] * (v0[0] - lfp.x) + h0[1] * (v0[1] - v0[0]);
        n0[1] = v0[1] - ca[1] * (v0[1] - up.y) + cm[1] * (v1[1] - v0[1])
                      - h0[1] * (v0[1] - v0[0]) + h0[2] * (v0[2] - v0[1]);
        n0[2] = v0[2] - ca[2] * (v0[2] - up.z) + cm[2] * (v1[2] - v0[2])
                      - h0[2] * (v0[2] - v0[1]) + h0[3] * (v0[3] - v0[2]);
        n0[3] = v0[3] - ca[3] * (v0[3] - up.w) + cm[3] * (v1[3] - v0[3])
                      - h0[3] * (v0[3] - v0[2]) + h0[4] * (rtp.x - v0[3]);
        n1[0] = v1[0] - cm[0] * (v1[0] - v0[0]) + cb[0] * (dn.x - v1[0])
                      - h1[0] * (v1[0] - lfp.y) + h1[1] * (v1[1] - v1[0]);
        n1[1] = v1[1] - cm[1] * (v1[1] - v0[1]) + cb[1] * (dn.y - v1[1])
                      - h1[1] * (v1[1] - v1[0]) + h1[2] * (v1[2] - v1[1]);
        n1[2] = v1[2] - cm[2] * (v1[2] - v0[2]) + cb[2] * (dn.z - v1[2])
                      - h1[2] * (v1[2] - v1[1]) + h1[3] * (v1[3] - v1[2]);
        n1[3] = v1[3] - cm[3] * (v1[3] - v0[3]) + cb[3] * (dn.w - v1[3])
                      - h1[3] * (v1[3] - v1[2]) + h1[4] * (rtp.y - v1[3]);
        int nxt = cur ^ 1;
        float* d = sb[nxt];
        *reinterpret_cast<float4*>(&d[roff0]) = float4{n0[0], n0[1], n0[2], n0[3]};
        *reinterpret_cast<float4*>(&d[roff1]) = float4{n1[0], n1[1], n1[2], n1[3]};
        *reinterpret_cast<float4*>(&d[e_w])   = float4{n0[0], n1[0], n0[3], n1[3]};
        v0[0] = n0[0]; v0[1] = n0[1]; v0[2] = n0[2]; v0[3] = n0[3];
        v1[0] = n1[0]; v1[1] = n1[1]; v1[2] = n1[2]; v1[3] = n1[3];
        cur = nxt;
        __syncthreads();
    }
    float* dstb = dst + b * IMG;
    if (is_int) {
        float4 o0{v0[0], v0[1], v0[2], v0[3]};
        float4 o1{v1[0], v1[1], v1[2], v1[3]};
        if (SUB_SHIFT) {
            o0.x -= shift; o0.y -= shift; o0.z -= shift; o0.w -= shift;
            o1.x -= shift; o1.y -= shift; o1.z -= shift; o1.w -= shift;
        }
        *reinterpret_cast<float4*>(dstb + goff0) = o0;
        *reinterpret_cast<float4*>(dstb + goff1) = o1;
    }
}

// -------- fallback (round-2 verified, inline gather, 256 threads) --------
template <bool ADD_SHIFT, bool SUB_SHIFT>
__global__ __launch_bounds__(256, 1) void step_fused(
    const float* __restrict__ src, float* __restrict__ dst,
    const float* __restrict__ cv_g, const float* __restrict__ ch_g,
    const unsigned* __restrict__ key) {
    __shared__ float sb[2][SSZ];
    const int blk = blockIdx.x;
    const int b = blk >> 7, t = blk & 127;
    const int y0 = (t >> 3) * TILE_H, x0 = (t & 7) * TILE_W;
    const float* cvb = cv_g + b * CV_PER_B;
    const float* chb = ch_g + b * CH_PER_B;
    const float* srcb = src + b * IMG;
    float* dstb = dst + b * IMG;
    float shift = 0.f;
    if (ADD_SHIFT || SUB_SHIFT) shift = (kinv(*key) <= DEPS_) ? DEPS_ : 0.f;
    const int tid = threadIdx.x;
    float v[QPT_F][4], cu[QPT_F][4], cd[QPT_F][4], chq[QPT_F][5];
    int roff[QPT_F], rr[QPT_F], xx[QPT_F];
    bool act[QPT_F];
#pragma unroll
    for (int q = 0; q < QPT_F; ++q) {
        int qi = tid + q * 256;
        act[q] = qi < NQUAD;
        int qc = act[q] ? qi : 0;
        int r = qc / NQ_ROW;
        int x = (qc - r * NQ_ROW) * 4;
        rr[q] = r; xx[q] = x;
        roff[q] = (r + 1) * RW + x;
        int gy = y0 - HALO_Y + r, gx = x0 - HALO_X + x;
        bool gy_in = (gy >= 0) && (gy < HH);
#pragma unroll
        for (int j = 0; j < 4; ++j) {
            int gxx = gx + j;
            bool gx_in = (gxx >= 0) && (gxx < WW);
            bool vin = act[q] && gy_in && gx_in;
            float val = vin ? srcb[gy * WW + gxx] : 0.f;
            if (ADD_SHIFT) val += shift;
            v[q][j] = vin ? val : 0.f;
            bool up_ok = act[q] && (r >= 1) && (gy >= 1) && (gy < HH) && gx_in;
            cu[q][j] = up_ok ? LAM * cvb[(gy - 1) * WW + gxx] : 0.f;
            bool dn_ok = act[q] && (r <= RH - 2) && (gy >= 0) && (gy < HH - 1) && gx_in;
            cd[q][j] = dn_ok ? LAM * cvb[gy * WW + gxx] : 0.f;
        }
#pragma unroll
        for (int jj = 0; jj < 5; ++jj) {
            int xe = x + jj, gxe = gx + jj;
            bool ok = act[q] && (xe >= 1) && (xe <= RW - 1) && gy_in &&
                      (gxe >= 1) && (gxe < WW);
            chq[q][jj] = ok ? LAM * chb[gy * (WW - 1) + (gxe - 1)] : 0.f;
        }
    }
    for (int i = tid; i < RW; i += 256) {
        sb[0][i] = 0.f; sb[0][(RH + 1) * RW + i] = 0.f;
        sb[1][i] = 0.f; sb[1][(RH + 1) * RW + i] = 0.f;
    }
#pragma unroll
    for (int q = 0; q < QPT_F; ++q)
        if (act[q])
            *reinterpret_cast<float4*>(&sb[0][roff[q]]) =
                float4{v[q][0], v[q][1], v[q][2], v[q][3]};
    __syncthreads();
    int cur = 0;
    for (int it = 0; it < T_FUSE; ++it) {
        float nv[QPT_F][4];
#pragma unroll
        for (int q = 0; q < QPT_F; ++q) {
            const float* s = sb[cur];
            float4 up = *reinterpret_cast<const float4*>(&s[roff[q] - RW]);
            float4 dn = *reinterpret_cast<const float4*>(&s[roff[q] + RW]);
            float lf = s[roff[q] - 1];
            float rt = s[roff[q] + 4];
            float c0 = v[q][0], c1 = v[q][1], c2 = v[q][2], c3 = v[q][3];
            nv[q][0] = c0 - cu[q][0] * (c0 - up.x) + cd[q][0] * (dn.x - c0)
                          - chq[q][0] * (c0 - lf) + chq[q][1] * (c1 - c0);
            nv[q][1] = c1 - cu[q][1] * (c1 - up.y) + cd[q][1] * (dn.y - c1)
                          - chq[q][1] * (c1 - c0) + chq[q][2] * (c2 - c1);
            nv[q][2] = c2 - cu[q][2] * (c2 - up.z) + cd[q][2] * (dn.z - c2)
                          - chq[q][2] * (c2 - c1) + chq[q][3] * (c3 - c2);
            nv[q][3] = c3 - cu[q][3] * (c3 - up.w) + cd[q][3] * (dn.w - c3)
                          - chq[q][3] * (c3 - c2) + chq[q][4] * (rt - c3);
        }
        int nxt = cur ^ 1;
#pragma unroll
        for (int q = 0; q < QPT_F; ++q) {
            if (act[q])
                *reinterpret_cast<float4*>(&sb[nxt][roff[q]]) =
                    float4{nv[q][0], nv[q][1], nv[q][2], nv[q][3]};
            v[q][0] = nv[q][0]; v[q][1] = nv[q][1];
            v[q][2] = nv[q][2]; v[q][3] = nv[q][3];
        }
        cur = nxt;
        __syncthreads();
    }
#pragma unroll
    for (int q = 0; q < QPT_F; ++q) {
        if (!act[q]) continue;
        int r = rr[q], x = xx[q];
        if (r >= HALO_Y && r < HALO_Y + TILE_H && x >= HALO_X && x < HALO_X + TILE_W) {
            int gy = y0 - HALO_Y + r, gx = x0 - HALO_X + x;
            float4 o{v[q][0], v[q][1], v[q][2], v[q][3]};
            if (SUB_SHIFT) { o.x -= shift; o.y -= shift; o.z -= shift; o.w -= shift; }
            *reinterpret_cast<float4*>(dstb + gy * WW + gx) = o;
        }
    }
}

extern "C" void kernel_launch(void* const* d_in, const int* in_sizes, int n_in,
                              void* d_out, int out_size, void* d_ws, size_t ws_size,
                              hipStream_t stream) {
    const float* guide   = (const float*)d_in[0];
    const float* initial = (const float*)d_in[1];
    float* out    = (float*)d_out;
    float* out_y  = out;
    float* out_cv = out + N_DEPTH;
    float* out_ch = out + N_DEPTH + N_CV;

    unsigned* key = (unsigned*)d_ws;
    float* wsf    = (float*)d_ws;
    float* bufA   = wsf + 64;
    float* bufB   = bufA + N_DEPTH;
    float* blob   = bufB + N_DEPTH;
    unsigned* flags = (unsigned*)(blob + 256 * BLOB_BLK);

    const size_t need = (size_t)(64 + 2 * N_DEPTH + 256 * BLOB_BLK + 256) * 4;
    const bool fast = ws_size >= need;

    hipLaunchKernelGGL(init_key_kernel, dim3(1), dim3(256), 0, stream, key, flags);
    hipLaunchKernelGGL(min_kernel, dim3(256), dim3(256), 0, stream, initial, key);

    int nco = N_CV + N_CH;
    hipLaunchKernelGGL(coeff_kernel, dim3((nco + 255) / 256), dim3(256), 0, stream,
                       guide, out_cv, out_ch);

    if (fast) {
        hipLaunchKernelGGL(prep_planes, dim3(256), dim3(256), 0, stream,
                           out_cv, out_ch, blob);
        const float* a0 = initial;
        float* a1 = out_y;
        float* a2 = bufA;
        float* a3 = bufB;
        const float* a4 = blob;
        const unsigned* a5 = key;
        unsigned* a6 = flags;
        void* kargs[] = {&a0, &a1, &a2, &a3, &a4, &a5, &a6};
        hipError_t ce = hipLaunchCooperativeKernel(
            (const void*)diffuse_persist, dim3(256), dim3(NTF), kargs, 0, stream);
        if (ce == hipSuccess) return;
        // cooperative unsupported -> verified R7 relaunch path
        float* bufs[2] = {bufA, bufB};
        for (int k = 0; k < NSS; ++k) {
            const float* src = (k == 0) ? initial : bufs[(k + 1) & 1];
            float*       dst = (k == NSS - 1) ? out_y : bufs[k & 1];
            if (k == 0)
                hipLaunchKernelGGL((step_fast<true, false>), dim3(256), dim3(NTF), 0,
                                   stream, src, dst, blob, key);
            else if (k == NSS - 1)
                hipLaunchKernelGGL((step_fast<false, true>), dim3(256), dim3(NTF), 0,
                                   stream, src, dst, blob, key);
            else
                hipLaunchKernelGGL((step_fast<false, false>), dim3(256), dim3(NTF), 0,
                                   stream, src, dst, blob, key);
        }
        return;
    }

    float* bufs[2] = {bufA, bufB};
    for (int k = 0; k < NSS; ++k) {
        const float* src = (k == 0) ? initial : bufs[(k + 1) & 1];
        float*       dst = (k == NSS - 1) ? out_y : bufs[k & 1];
        if (k == 0)
            hipLaunchKernelGGL((step_fused<true, false>), dim3(256), dim3(256), 0,
                               stream, src, dst, out_cv, out_ch, key);
        else if (k == NSS - 1)
            hipLaunchKernelGGL((step_fused<false, true>), dim3(256), dim3(256), 0,
                               stream, src, dst, out_cv, out_ch, key);
        else
            hipLaunchKernelGGL((step_fused<false, false>), dim3(256), dim3(256), 0,
                               stream, src, dst, out_cv, out_ch, key);
    }
}

// Round 9
// 470.319 us; speedup vs baseline: 6.2492x; 1.0346x over previous
//
#include <hip/hip_runtime.h>

// Perona-Malik diffusion, 500 iters. Round-13: persistent v3 (prologue fusion).
// R12 confirmed: per-access coherent exchange (no fences) gives 403us persist,
// 486us total = best. This round removes the remaining fixed overhead:
//  (a) prep_planes + 9.9MB blob DELETED -- persist gathers its coefficients
//      directly from out_cv/out_ch ONCE in the prologue with the R2-verified
//      predicates (same values, same LAM multiply, same zero-predication ->
//      bit-identical);
//  (b) min_kernel merged into coeff_kernel (disjoint block ranges, 1 launch);
//  (c) spin without s_sleep (lower flag-detect latency).
// Sync design unchanged from R12: interior writes + halo reads are 8B
// agent-scope relaxed atomics (sc-bit ops to the coherence point, L2 stays
// clean); per-thread s_waitcnt vmcnt(0) + barrier before tid0 posts the
// per-block progress flag; neighbors spin on <=8 flags. Fallback: coop-launch
// failure -> R2-verified step_fused relaunch loop.

#define HH 512
#define WW 512
#define NB 2
static constexpr float LAM   = 0.24f;
static constexpr float KCOND = 0.03f;
static constexpr float DEPS_ = 0.1f;
static constexpr int IMG      = HH * WW;
static constexpr int N_DEPTH  = NB * IMG;
static constexpr int CV_PER_B = (HH - 1) * WW;
static constexpr int CH_PER_B = HH * (WW - 1);
static constexpr int N_CV     = NB * CV_PER_B;
static constexpr int N_CH     = NB * CH_PER_B;

static constexpr int T_FUSE = 10, NSS = 50;       // 50 x 10 = 500
static constexpr int TILE_W = 64, TILE_H = 32;
static constexpr int HALO_X = 12, HALO_Y = 10;
static constexpr int RW = TILE_W + 2 * HALO_X;    // 88
static constexpr int RH = TILE_H + 2 * HALO_Y;    // 52
static constexpr int NQ_ROW = RW / 4;             // 22
static constexpr int NQUAD  = NQ_ROW * RH;        // 1144 (fallback)
static constexpr int SSZ    = (RH + 2) * RW;      // fallback layout (4752)

// persistent path: 4x2 units, one per thread (R7 geometry)
static constexpr int NU_ROW = RW / 4;              // 22 units per row-pair
static constexpr int NU_COL = RH / 2;              // 26 row-pairs
static constexpr int NUNIT  = NU_ROW * NU_COL;     // 572
static constexpr int NTF    = 576;                 // 9 waves

// LDS layout (floats), per ping-pong buffer (R7):
static constexpr int S_LDS    = 92;
static constexpr int ROWS_SZ  = (RH + 2) * S_LDS;       // 4968
static constexpr int TRASH_OFF = ROWS_SZ;               // 4968
static constexpr int EDGE_OFF = ROWS_SZ + S_LDS;        // 5060 (16B aligned)
static constexpr int EDGE_ENT = 580;                    // entries 0..577 used
static constexpr int BUF_SZ   = EDGE_OFF + EDGE_ENT * 4; // 7380

// fallback path (round-2 verified): 256 threads, 5 quads/thread
static constexpr int QPT_F = 5;

// ---- monotone float<->uint key for atomic min ----
__device__ __forceinline__ unsigned fkey(float f) {
    unsigned u = __float_as_uint(f);
    return (u & 0x80000000u) ? ~u : (u | 0x80000000u);
}
__device__ __forceinline__ float kinv(unsigned k) {
    return __uint_as_float((k & 0x80000000u) ? (k & 0x7fffffffu) : ~k);
}

// ---- per-access coherent 8B load/store (agent scope, relaxed) ----
__device__ __forceinline__ float2 cohload8(const float* p) {
    unsigned long long u = __hip_atomic_load(
        reinterpret_cast<const unsigned long long*>(p),
        __ATOMIC_RELAXED, __HIP_MEMORY_SCOPE_AGENT);
    union { unsigned long long u; float2 f; } c; c.u = u;
    return c.f;
}
__device__ __forceinline__ void cohstore8(float* p, float a, float b) {
    union { unsigned long long u; float f[2]; } c;
    c.f[0] = a; c.f[1] = b;
    __hip_atomic_store(reinterpret_cast<unsigned long long*>(p), c.u,
                       __ATOMIC_RELAXED, __HIP_MEMORY_SCOPE_AGENT);
}

__global__ void init_key_kernel(unsigned* key, unsigned* flags) {
    if (threadIdx.x == 0) *key = 0xFFFFFFFFu;
    flags[threadIdx.x] = 0u;   // 256 threads, one flag per persistent block
}

// coeff (blocks [0, NCO_BLK)) + min-reduction (blocks [NCO_BLK, NCO_BLK+256))
static constexpr int NCO_BLK = (N_CV + N_CH + 255) / 256;
__global__ void coeff_min_kernel(const float* __restrict__ g,
                                 const float* __restrict__ ini,
                                 float* __restrict__ cv, float* __restrict__ chh,
                                 unsigned* __restrict__ key) {
    constexpr float kk = KCOND * KCOND;
    if ((int)blockIdx.x >= NCO_BLK) {
        // ---- min over initial ----
        int bid = blockIdx.x - NCO_BLK;
        float m = 3.4e38f;
        for (int idx = bid * 256 + threadIdx.x; idx < N_DEPTH; idx += 256 * 256)
            m = fminf(m, ini[idx]);
        for (int off = 32; off > 0; off >>= 1) m = fminf(m, __shfl_down(m, off, 64));
        __shared__ float sm[4];
        int lane = threadIdx.x & 63, wv = threadIdx.x >> 6;
        if (lane == 0) sm[wv] = m;
        __syncthreads();
        if (threadIdx.x == 0) {
            float mm = fminf(fminf(sm[0], sm[1]), fminf(sm[2], sm[3]));
            atomicMin(key, fkey(mm));
        }
        return;
    }
    int idx = blockIdx.x * 256 + threadIdx.x;
    if (idx < N_CV) {
        int b = idx / CV_PER_B;
        int r = idx - b * CV_PER_B;
        int i = r >> 9, j = r & (WW - 1);
        const float* gb = g + b * 3 * IMG + i * WW + j;
        float s = 0.f;
#pragma unroll
        for (int c = 0; c < 3; ++c) s += fabsf(gb[c * IMG + WW] - gb[c * IMG]);
        float m = s / 3.0f;
        cv[idx] = 1.0f / (1.0f + (m * m) / kk);
    } else if (idx < N_CV + N_CH) {
        int t = idx - N_CV;
        int b = t / CH_PER_B;
        int r = t - b * CH_PER_B;
        int i = r / (WW - 1);
        int j = r - i * (WW - 1);
        const float* gb = g + b * 3 * IMG + i * WW + j;
        float s = 0.f;
#pragma unroll
        for (int c = 0; c < 3; ++c) s += fabsf(gb[c * IMG + 1] - gb[c * IMG]);
        float m = s / 3.0f;
        chh[t] = 1.0f / (1.0f + (m * m) / kk);
    }
}

// ================= persistent cooperative kernel (v3) =================
__global__ __launch_bounds__(NTF, 1) void diffuse_persist(
    const float* __restrict__ initial, float* __restrict__ out_y,
    float* __restrict__ bufA, float* __restrict__ bufB,
    const float* __restrict__ cv_g, const float* __restrict__ ch_g,
    const unsigned* __restrict__ key, unsigned* __restrict__ flags) {
    __shared__ float sb[2][BUF_SZ];
    const int blk = blockIdx.x;
    const int b   = blk >> 7, t = blk & 127;
    const int ty  = t >> 3, tx = t & 7;
    const int y0  = ty * TILE_H;
    const int x0  = tx * TILE_W;
    const float shift = (kinv(*key) <= DEPS_) ? DEPS_ : 0.f;
    const int tid = threadIdx.x;

    // ---- unit geometry: 4 wide x 2 tall (R7) ----
    const bool act = tid < NUNIT;
    const int  uc  = act ? tid : 0;
    const int  pr  = uc / NU_ROW;
    const int  px  = uc - pr * NU_ROW;
    const int  x   = px * 4;
    const int  r0  = 2 * pr, r1 = r0 + 1;
    int roff0 = (r0 + 1) * S_LDS + x;
    int roff1 = roff0 + S_LDS;
    if (!act) { roff0 = TRASH_OFF + (tid & 3) * 8; roff1 = roff0 + 4; }
    const int e_w  = EDGE_OFF + (tid + 1) * 4;
    const int e_lf = EDGE_OFF + tid * 4 + 2;
    const int e_rt = EDGE_OFF + (tid + 2) * 4;

    const int gy0 = y0 - HALO_Y + r0, gy1 = gy0 + 1;
    const int gx  = x0 - HALO_X + x;
    const bool gx_in = (gx >= 0) && (gx <= WW - 4);
    const bool in0 = act && gx_in && (gy0 >= 0) && (gy0 < HH);
    const bool in1 = act && gx_in && (gy1 >= 0) && (gy1 < HH);
    const int goff0 = in0 ? (gy0 * WW + gx) : 0;
    const int goff1 = in1 ? (gy1 * WW + gx) : 0;
    const bool is_int = act && (r0 >= HALO_Y) && (r1 < HALO_Y + TILE_H) &&
                        (x >= HALO_X) && (x < HALO_X + TILE_W);

    // ---- coefficients ONCE: inline gather, R2-verified predicates ----
    // (identical values to the old baked planes: LAM*cv / LAM*ch, zero
    //  outside validity -> bit-identical iteration)
    const float* cvb = cv_g + b * CV_PER_B;
    const float* chb = ch_g + b * CH_PER_B;
    float ca[4], cm[4], cb[4], h0[5], h1[5];
#pragma unroll
    for (int j = 0; j < 4; ++j) {
        int gxx = gx + j;
        bool gxo = (gxx >= 0) && (gxx < WW);
        bool a_ok = act && (r0 >= 1) && (gy0 >= 1) && (gy0 <= HH - 1) && gxo;
        ca[j] = a_ok ? LAM * cvb[(gy0 - 1) * WW + gxx] : 0.f;
        bool m_ok = act && (gy1 >= 1) && (gy1 <= HH - 1) && gxo;  // r1>=1 always
        cm[j] = m_ok ? LAM * cvb[(gy1 - 1) * WW + gxx] : 0.f;
        bool b_ok = act && (r1 <= RH - 2) && (gy1 + 1 >= 1) && (gy1 + 1 <= HH - 1) && gxo;
        cb[j] = b_ok ? LAM * cvb[gy1 * WW + gxx] : 0.f;
    }
#pragma unroll
    for (int jj = 0; jj < 5; ++jj) {
        int xe = x + jj, gxe = gx + jj;
        bool e_ok = (xe >= 1) && (xe <= RW - 1) && (gxe >= 1) && (gxe < WW);
        bool ok0 = act && e_ok && (gy0 >= 0) && (gy0 < HH);
        h0[jj] = ok0 ? LAM * chb[gy0 * (WW - 1) + (gxe - 1)] : 0.f;
        bool ok1 = act && e_ok && (gy1 >= 0) && (gy1 < HH);
        h1[jj] = ok1 ? LAM * chb[gy1 * (WW - 1) + (gxe - 1)] : 0.f;
    }

    // ---- neighbor flag index (tid<8 -> one of 8 neighbors) ----
    int nbr = -1;
    if (tid < 8) {
        int d  = tid + (tid >= 4 ? 1 : 0);      // 0..8 skipping center(4)
        int dy = d / 3 - 1, dx = d % 3 - 1;
        int ny = ty + dy, nx = tx + dx;
        if (ny >= 0 && ny < 16 && nx >= 0 && nx < 8)
            nbr = (b << 7) + (ny << 3) + nx;
    }

    // ---- superstep-0 full load (+shift) ----
    float v0[4] = {0.f, 0.f, 0.f, 0.f}, v1[4] = {0.f, 0.f, 0.f, 0.f};
    const float* ib = initial + b * IMG;
    if (in0) {
        float4 tv = *reinterpret_cast<const float4*>(ib + goff0);
        v0[0] = tv.x + shift; v0[1] = tv.y + shift; v0[2] = tv.z + shift; v0[3] = tv.w + shift;
    }
    if (in1) {
        float4 tv = *reinterpret_cast<const float4*>(ib + goff1);
        v1[0] = tv.x + shift; v1[1] = tv.y + shift; v1[2] = tv.z + shift; v1[3] = tv.w + shift;
    }

    // guard rows + edge sentinels (once; they stay valid across supersteps)
    for (int i = tid; i < S_LDS; i += NTF) {
        sb[0][i] = 0.f; sb[0][(RH + 1) * S_LDS + i] = 0.f;
        sb[1][i] = 0.f; sb[1][(RH + 1) * S_LDS + i] = 0.f;
    }
    if (tid == 0) {
        float4 z{0.f, 0.f, 0.f, 0.f};
        *reinterpret_cast<float4*>(&sb[0][EDGE_OFF]) = z;
        *reinterpret_cast<float4*>(&sb[1][EDGE_OFF]) = z;
        *reinterpret_cast<float4*>(&sb[0][EDGE_OFF + 577 * 4]) = z;
        *reinterpret_cast<float4*>(&sb[1][EDGE_OFF + 577 * 4]) = z;
    }
    *reinterpret_cast<float4*>(&sb[0][roff0]) = float4{v0[0], v0[1], v0[2], v0[3]};
    *reinterpret_cast<float4*>(&sb[0][roff1]) = float4{v1[0], v1[1], v1[2], v1[3]};
    *reinterpret_cast<float4*>(&sb[0][e_w])   = float4{v0[0], v1[0], v0[3], v1[3]};
    __syncthreads();

    for (int k = 0; k < NSS; ++k) {
        if (k > 0) {
            // wait: 8 neighbors must have COMPLETED superstep k-1
            if (nbr >= 0) {
                while (__hip_atomic_load(&flags[nbr], __ATOMIC_RELAXED,
                                         __HIP_MEMORY_SCOPE_AGENT) < (unsigned)k) {}
            }
            __syncthreads();
            asm volatile("" ::: "memory");   // no compiler reordering past spin
            // halo units reload via coherent loads; interior persists
            const float* srcb = ((k & 1) ? bufA : bufB) + b * IMG;
            if (act && !is_int) {
                float2 a0{0.f, 0.f}, b0{0.f, 0.f}, a1{0.f, 0.f}, b1{0.f, 0.f};
                if (in0) { a0 = cohload8(srcb + goff0); b0 = cohload8(srcb + goff0 + 2); }
                if (in1) { a1 = cohload8(srcb + goff1); b1 = cohload8(srcb + goff1 + 2); }
                v0[0] = a0.x; v0[1] = a0.y; v0[2] = b0.x; v0[3] = b0.y;
                v1[0] = a1.x; v1[1] = a1.y; v1[2] = b1.x; v1[3] = b1.y;
                *reinterpret_cast<float4*>(&sb[0][roff0]) =
                    float4{v0[0], v0[1], v0[2], v0[3]};
                *reinterpret_cast<float4*>(&sb[0][roff1]) =
                    float4{v1[0], v1[1], v1[2], v1[3]};
                *reinterpret_cast<float4*>(&sb[0][e_w]) =
                    float4{v0[0], v1[0], v0[3], v1[3]};
            }
            __syncthreads();
        }

        int cur = 0;
        for (int it = 0; it < T_FUSE; ++it) {
            const float* s = sb[cur];
            float2 lfp = *reinterpret_cast<const float2*>(&s[e_lf]);
            float2 rtp = *reinterpret_cast<const float2*>(&s[e_rt]);
            float4 up = *reinterpret_cast<const float4*>(&s[roff0 - S_LDS]);
            float4 dn = *reinterpret_cast<const float4*>(&s[roff1 + S_LDS]);

            float n0[4], n1[4];
            n0[0] = v0[0] - ca[0] * (v0[0] - up.x) + cm[0] * (v1[0] - v0[0])
                          - h0[0] * (v0[0] - lfp.x) + h0[1] * (v0[1] - v0[0]);
            n0[1] = v0[1] - ca[1] * (v0[1] - up.y) + cm[1] * (v1[1] - v0[1])
                          - h0[1] * (v0[1] - v0[0]) + h0[2] * (v0[2] - v0[1]);
            n0[2] = v0[2] - ca[2] * (v0[2] - up.z) + cm[2] * (v1[2] - v0[2])
                          - h0[2] * (v0[2] - v0[1]) + h0[3] * (v0[3] - v0[2]);
            n0[3] = v0[3] - ca[3] * (v0[3] - up.w) + cm[3] * (v1[3] - v0[3])
                          - h0[3] * (v0[3] - v0[2]) + h0[4] * (rtp.x - v0[3]);
            n1[0] = v1[0] - cm[0] * (v1[0] - v0[0]) + cb[0] * (dn.x - v1[0])
                          - h1[0] * (v1[0] - lfp.y) + h1[1] * (v1[1] - v1[0]);
            n1[1] = v1[1] - cm[1] * (v1[1] - v0[1]) + cb[1] * (dn.y - v1[1])
                          - h1[1] * (v1[1] - v1[0]) + h1[2] * (v1[2] - v1[1]);
            n1[2] = v1[2] - cm[2] * (v1[2] - v0[2]) + cb[2] * (dn.z - v1[2])
                          - h1[2] * (v1[2] - v1[1]) + h1[3] * (v1[3] - v1[2]);
            n1[3] = v1[3] - cm[3] * (v1[3] - v0[3]) + cb[3] * (dn.w - v1[3])
                          - h1[3] * (v1[3] - v1[2]) + h1[4] * (rtp.y - v1[3]);

            int nxt = cur ^ 1;
            float* d = sb[nxt];
            *reinterpret_cast<float4*>(&d[roff0]) = float4{n0[0], n0[1], n0[2], n0[3]};
            *reinterpret_cast<float4*>(&d[roff1]) = float4{n1[0], n1[1], n1[2], n1[3]};
            *reinterpret_cast<float4*>(&d[e_w])   = float4{n0[0], n1[0], n0[3], n1[3]};
            v0[0] = n0[0]; v0[1] = n0[1]; v0[2] = n0[2]; v0[3] = n0[3];
            v1[0] = n1[0]; v1[1] = n1[1]; v1[2] = n1[2]; v1[3] = n1[3];
            cur = nxt;
            __syncthreads();
        }
        // T_FUSE even -> final values live in sb[0]; LDS stays valid for k+1.

        if (k == NSS - 1) {
            float* dstb = out_y + b * IMG;
            if (is_int) {
                float4 o0{v0[0] - shift, v0[1] - shift, v0[2] - shift, v0[3] - shift};
                float4 o1{v1[0] - shift, v1[1] - shift, v1[2] - shift, v1[3] - shift};
                *reinterpret_cast<float4*>(dstb + goff0) = o0;
                *reinterpret_cast<float4*>(dstb + goff1) = o1;
            }
        } else {
            float* dstb = ((k & 1) ? bufB : bufA) + b * IMG;
            if (is_int) {
                cohstore8(dstb + goff0,     v0[0], v0[1]);
                cohstore8(dstb + goff0 + 2, v0[2], v0[3]);
                cohstore8(dstb + goff1,     v1[0], v1[1]);
                cohstore8(dstb + goff1 + 2, v1[2], v1[3]);
            }
            // drain own coherent stores, then barrier orders all before flag
            asm volatile("s_waitcnt vmcnt(0)" ::: "memory");
            __syncthreads();
            if (tid == 0)
                __hip_atomic_store(&flags[blk], (unsigned)(k + 1),
                                   __ATOMIC_RELAXED, __HIP_MEMORY_SCOPE_AGENT);
        }
    }
}

// -------- fallback (round-2 verified, inline gather, 256 threads) --------
template <bool ADD_SHIFT, bool SUB_SHIFT>
__global__ __launch_bounds__(256, 1) void step_fused(
    const float* __restrict__ src, float* __restrict__ dst,
    const float* __restrict__ cv_g, const float* __restrict__ ch_g,
    const unsigned* __restrict__ key) {
    __shared__ float sb[2][SSZ];
    const int blk = blockIdx.x;
    const int b = blk >> 7, t = blk & 127;
    const int y0 = (t >> 3) * TILE_H, x0 = (t & 7) * TILE_W;
    const float* cvb = cv_g + b * CV_PER_B;
    const float* chb = ch_g + b * CH_PER_B;
    const float* srcb = src + b * IMG;
    float* dstb = dst + b * IMG;
    float shift = 0.f;
    if (ADD_SHIFT || SUB_SHIFT) shift = (kinv(*key) <= DEPS_) ? DEPS_ : 0.f;
    const int tid = threadIdx.x;
    float v[QPT_F][4], cu[QPT_F][4], cd[QPT_F][4], chq[QPT_F][5];
    int roff[QPT_F], rr[QPT_F], xx[QPT_F];
    bool act[QPT_F];
#pragma unroll
    for (int q = 0; q < QPT_F; ++q) {
        int qi = tid + q * 256;
        act[q] = qi < NQUAD;
        int qc = act[q] ? qi : 0;
        int r = qc / NQ_ROW;
        int x = (qc - r * NQ_ROW) * 4;
        rr[q] = r; xx[q] = x;
        roff[q] = (r + 1) * RW + x;
        int gy = y0 - HALO_Y + r, gx = x0 - HALO_X + x;
        bool gy_in = (gy >= 0) && (gy < HH);
#pragma unroll
        for (int j = 0; j < 4; ++j) {
            int gxx = gx + j;
            bool gx_in = (gxx >= 0) && (gxx < WW);
            bool vin = act[q] && gy_in && gx_in;
            float val = vin ? srcb[gy * WW + gxx] : 0.f;
            if (ADD_SHIFT) val += shift;
            v[q][j] = vin ? val : 0.f;
            bool up_ok = act[q] && (r >= 1) && (gy >= 1) && (gy < HH) && gx_in;
            cu[q][j] = up_ok ? LAM * cvb[(gy - 1) * WW + gxx] : 0.f;
            bool dn_ok = act[q] && (r <= RH - 2) && (gy >= 0) && (gy < HH - 1) && gx_in;
            cd[q][j] = dn_ok ? LAM * cvb[gy * WW + gxx] : 0.f;
        }
#pragma unroll
        for (int jj = 0; jj < 5; ++jj) {
            int xe = x + jj, gxe = gx + jj;
            bool ok = act[q] && (xe >= 1) && (xe <= RW - 1) && gy_in &&
                      (gxe >= 1) && (gxe < WW);
            chq[q][jj] = ok ? LAM * chb[gy * (WW - 1) + (gxe - 1)] : 0.f;
        }
    }
    for (int i = tid; i < RW; i += 256) {
        sb[0][i] = 0.f; sb[0][(RH + 1) * RW + i] = 0.f;
        sb[1][i] = 0.f; sb[1][(RH + 1) * RW + i] = 0.f;
    }
#pragma unroll
    for (int q = 0; q < QPT_F; ++q)
        if (act[q])
            *reinterpret_cast<float4*>(&sb[0][roff[q]]) =
                float4{v[q][0], v[q][1], v[q][2], v[q][3]};
    __syncthreads();
    int cur = 0;
    for (int it = 0; it < T_FUSE; ++it) {
        float nv[QPT_F][4];
#pragma unroll
        for (int q = 0; q < QPT_F; ++q) {
            const float* s = sb[cur];
            float4 up = *reinterpret_cast<const float4*>(&s[roff[q] - RW]);
            float4 dn = *reinterpret_cast<const float4*>(&s[roff[q] + RW]);
            float lf = s[roff[q] - 1];
            float rt = s[roff[q] + 4];
            float c0 = v[q][0], c1 = v[q][1], c2 = v[q][2], c3 = v[q][3];
            nv[q][0] = c0 - cu[q][0] * (c0 - up.x) + cd[q][0] * (dn.x - c0)
                          - chq[q][0] * (c0 - lf) + chq[q][1] * (c1 - c0);
            nv[q][1] = c1 - cu[q][1] * (c1 - up.y) + cd[q][1] * (dn.y - c1)
                          - chq[q][1] * (c1 - c0) + chq[q][2] * (c2 - c1);
            nv[q][2] = c2 - cu[q][2] * (c2 - up.z) + cd[q][2] * (dn.z - c2)
                          - chq[q][2] * (c2 - c1) + chq[q][3] * (c3 - c2);
            nv[q][3] = c3 - cu[q][3] * (c3 - up.w) + cd[q][3] * (dn.w - c3)
                          - chq[q][3] * (c3 - c2) + chq[q][4] * (rt - c3);
        }
        int nxt = cur ^ 1;
#pragma unroll
        for (int q = 0; q < QPT_F; ++q) {
            if (act[q])
                *reinterpret_cast<float4*>(&sb[nxt][roff[q]]) =
                    float4{nv[q][0], nv[q][1], nv[q][2], nv[q][3]};
            v[q][0] = nv[q][0]; v[q][1] = nv[q][1];
            v[q][2] = nv[q][2]; v[q][3] = nv[q][3];
        }
        cur = nxt;
        __syncthreads();
    }
#pragma unroll
    for (int q = 0; q < QPT_F; ++q) {
        if (!act[q]) continue;
        int r = rr[q], x = xx[q];
        if (r >= HALO_Y && r < HALO_Y + TILE_H && x >= HALO_X && x < HALO_X + TILE_W) {
            int gy = y0 - HALO_Y + r, gx = x0 - HALO_X + x;
            float4 o{v[q][0], v[q][1], v[q][2], v[q][3]};
            if (SUB_SHIFT) { o.x -= shift; o.y -= shift; o.z -= shift; o.w -= shift; }
            *reinterpret_cast<float4*>(dstb + gy * WW + gx) = o;
        }
    }
}

extern "C" void kernel_launch(void* const* d_in, const int* in_sizes, int n_in,
                              void* d_out, int out_size, void* d_ws, size_t ws_size,
                              hipStream_t stream) {
    const float* guide   = (const float*)d_in[0];
    const float* initial = (const float*)d_in[1];
    float* out    = (float*)d_out;
    float* out_y  = out;
    float* out_cv = out + N_DEPTH;
    float* out_ch = out + N_DEPTH + N_CV;

    unsigned* key = (unsigned*)d_ws;
    float* wsf    = (float*)d_ws;
    float* bufA   = wsf + 64;
    float* bufB   = bufA + N_DEPTH;
    unsigned* flags = (unsigned*)(bufB + N_DEPTH);

    const size_t need = (size_t)(64 + 2 * N_DEPTH + 256) * 4;
    const bool fast = ws_size >= need;

    hipLaunchKernelGGL(init_key_kernel, dim3(1), dim3(256), 0, stream, key,
                       fast ? flags : (unsigned*)d_ws + 1);
    hipLaunchKernelGGL(coeff_min_kernel, dim3(NCO_BLK + 256), dim3(256), 0, stream,
                       guide, initial, out_cv, out_ch, key);

    if (fast) {
        const float* a0 = initial;
        float* a1 = out_y;
        float* a2 = bufA;
        float* a3 = bufB;
        const float* a4 = out_cv;
        const float* a5 = out_ch;
        const unsigned* a6 = key;
        unsigned* a7 = flags;
        void* kargs[] = {&a0, &a1, &a2, &a3, &a4, &a5, &a6, &a7};
        hipError_t ce = hipLaunchCooperativeKernel(
            (const void*)diffuse_persist, dim3(256), dim3(NTF), kargs, 0, stream);
        if (ce == hipSuccess) return;
    }

    // fallback: R2-verified relaunch loop
    float* bufs[2] = {bufA, bufB};
    for (int k = 0; k < NSS; ++k) {
        const float* src = (k == 0) ? initial : bufs[(k + 1) & 1];
        float*       dst = (k == NSS - 1) ? out_y : bufs[k & 1];
        if (k == 0)
            hipLaunchKernelGGL((step_fused<true, false>), dim3(256), dim3(256), 0,
                               stream, src, dst, out_cv, out_ch, key);
        else if (k == NSS - 1)
            hipLaunchKernelGGL((step_fused<false, true>), dim3(256), dim3(256), 0,
                               stream, src, dst, out_cv, out_ch, key);
        else
            hipLaunchKernelGGL((step_fused<false, false>), dim3(256), dim3(256), 0,
                               stream, src, dst, out_cv, out_ch, key);
    }
}

// Round 10
// 461.267 us; speedup vs baseline: 6.3718x; 1.0196x over previous
//
#include <hip/hip_runtime.h>

// Perona-Malik diffusion, 500 iters. Round-14: persistent v4 (sync trims).
// R13 landed prologue fusion (470us). This round:
//  (a) init_key launch DELETED: min-blocks write partials[bid] (no atomic,
//      no seed); persist reduces the 256 partials in its prologue (4-wave
//      shfl + LDS broadcast); flags[bid] zeroed by min-block bid.
//  (b) inner-cell coherent-store skip: interior cells >=12 cols / >=10 rows
//      from the tile edge (40x12 = 23% of interior) are never read by any
//      neighbor halo and persist in the owner's registers -- their coherent
//      stores were pure MALL traffic. Skipping them is invisible to the
//      data-flow (bit-identical).
//  (c) key/fkey machinery removed; fallback derives shift via a tiny
//      reduce kernel over partials.
// Sync design unchanged from R12/13: 8B agent-scope relaxed atomics for
// interior/halo exchange; per-thread vmcnt(0) drain + barrier before tid0
// posts the per-block progress flag; neighbors spin on <=8 flags.

#define HH 512
#define WW 512
#define NB 2
static constexpr float LAM   = 0.24f;
static constexpr float KCOND = 0.03f;
static constexpr float DEPS_ = 0.1f;
static constexpr int IMG      = HH * WW;
static constexpr int N_DEPTH  = NB * IMG;
static constexpr int CV_PER_B = (HH - 1) * WW;
static constexpr int CH_PER_B = HH * (WW - 1);
static constexpr int N_CV     = NB * CV_PER_B;
static constexpr int N_CH     = NB * CH_PER_B;

static constexpr int T_FUSE = 10, NSS = 50;       // 50 x 10 = 500
static constexpr int TILE_W = 64, TILE_H = 32;
static constexpr int HALO_X = 12, HALO_Y = 10;
static constexpr int RW = TILE_W + 2 * HALO_X;    // 88
static constexpr int RH = TILE_H + 2 * HALO_Y;    // 52
static constexpr int NQ_ROW = RW / 4;             // 22
static constexpr int NQUAD  = NQ_ROW * RH;        // 1144 (fallback)
static constexpr int SSZ    = (RH + 2) * RW;      // fallback layout (4752)

// persistent path: 4x2 units, one per thread (R7 geometry)
static constexpr int NU_ROW = RW / 4;              // 22 units per row-pair
static constexpr int NU_COL = RH / 2;              // 26 row-pairs
static constexpr int NUNIT  = NU_ROW * NU_COL;     // 572
static constexpr int NTF    = 576;                 // 9 waves

// LDS layout (floats), per ping-pong buffer (R7):
static constexpr int S_LDS    = 92;
static constexpr int ROWS_SZ  = (RH + 2) * S_LDS;       // 4968
static constexpr int TRASH_OFF = ROWS_SZ;               // 4968
static constexpr int EDGE_OFF = ROWS_SZ + S_LDS;        // 5060 (16B aligned)
static constexpr int EDGE_ENT = 580;                    // entries 0..577 used
static constexpr int BUF_SZ   = EDGE_OFF + EDGE_ENT * 4; // 7380
// scratch for the partial-min broadcast (inside sb[0] trash area, above the
// !act slots which only use TRASH_OFF..TRASH_OFF+31)
static constexpr int MIN_SCR  = TRASH_OFF + 40;

// fallback path (round-2 verified): 256 threads, 5 quads/thread
static constexpr int QPT_F = 5;

// ---- per-access coherent 8B load/store (agent scope, relaxed) ----
__device__ __forceinline__ float2 cohload8(const float* p) {
    unsigned long long u = __hip_atomic_load(
        reinterpret_cast<const unsigned long long*>(p),
        __ATOMIC_RELAXED, __HIP_MEMORY_SCOPE_AGENT);
    union { unsigned long long u; float2 f; } c; c.u = u;
    return c.f;
}
__device__ __forceinline__ void cohstore8(float* p, float a, float b) {
    union { unsigned long long u; float f[2]; } c;
    c.f[0] = a; c.f[1] = b;
    __hip_atomic_store(reinterpret_cast<unsigned long long*>(p), c.u,
                       __ATOMIC_RELAXED, __HIP_MEMORY_SCOPE_AGENT);
}

// coeff (blocks [0, NCO_BLK)) + min-partials (blocks [NCO_BLK, NCO_BLK+256))
static constexpr int NCO_BLK = (N_CV + N_CH + 255) / 256;
__global__ void coeff_min_kernel(const float* __restrict__ g,
                                 const float* __restrict__ ini,
                                 float* __restrict__ cv, float* __restrict__ chh,
                                 float* __restrict__ partials,
                                 unsigned* __restrict__ flags) {
    constexpr float kk = KCOND * KCOND;
    if ((int)blockIdx.x >= NCO_BLK) {
        // ---- partial min over initial (no atomics, no seed needed) ----
        int bid = blockIdx.x - NCO_BLK;
        if (threadIdx.x == 0) flags[bid] = 0u;   // zero the progress flag
        float m = 3.4e38f;
        for (int idx = bid * 256 + threadIdx.x; idx < N_DEPTH; idx += 256 * 256)
            m = fminf(m, ini[idx]);
        for (int off = 32; off > 0; off >>= 1) m = fminf(m, __shfl_down(m, off, 64));
        __shared__ float sm[4];
        int lane = threadIdx.x & 63, wv = threadIdx.x >> 6;
        if (lane == 0) sm[wv] = m;
        __syncthreads();
        if (threadIdx.x == 0)
            partials[bid] = fminf(fminf(sm[0], sm[1]), fminf(sm[2], sm[3]));
        return;
    }
    int idx = blockIdx.x * 256 + threadIdx.x;
    if (idx < N_CV) {
        int b = idx / CV_PER_B;
        int r = idx - b * CV_PER_B;
        int i = r >> 9, j = r & (WW - 1);
        const float* gb = g + b * 3 * IMG + i * WW + j;
        float s = 0.f;
#pragma unroll
        for (int c = 0; c < 3; ++c) s += fabsf(gb[c * IMG + WW] - gb[c * IMG]);
        float m = s / 3.0f;
        cv[idx] = 1.0f / (1.0f + (m * m) / kk);
    } else if (idx < N_CV + N_CH) {
        int t = idx - N_CV;
        int b = t / CH_PER_B;
        int r = t - b * CH_PER_B;
        int i = r / (WW - 1);
        int j = r - i * (WW - 1);
        const float* gb = g + b * 3 * IMG + i * WW + j;
        float s = 0.f;
#pragma unroll
        for (int c = 0; c < 3; ++c) s += fabsf(gb[c * IMG + 1] - gb[c * IMG]);
        float m = s / 3.0f;
        chh[t] = 1.0f / (1.0f + (m * m) / kk);
    }
}

// fallback helper: reduce 256 partials -> keyf (the min of initial)
__global__ void key_from_partials(const float* __restrict__ partials,
                                  float* __restrict__ keyf) {
    float m = partials[threadIdx.x];
    for (int off = 32; off > 0; off >>= 1) m = fminf(m, __shfl_down(m, off, 64));
    __shared__ float sm[4];
    int lane = threadIdx.x & 63, wv = threadIdx.x >> 6;
    if (lane == 0) sm[wv] = m;
    __syncthreads();
    if (threadIdx.x == 0)
        keyf[0] = fminf(fminf(sm[0], sm[1]), fminf(sm[2], sm[3]));
}

// ================= persistent cooperative kernel (v4) =================
__global__ __launch_bounds__(NTF, 1) void diffuse_persist(
    const float* __restrict__ initial, float* __restrict__ out_y,
    float* __restrict__ bufA, float* __restrict__ bufB,
    const float* __restrict__ cv_g, const float* __restrict__ ch_g,
    const float* __restrict__ partials, unsigned* __restrict__ flags) {
    __shared__ float sb[2][BUF_SZ];
    const int blk = blockIdx.x;
    const int b   = blk >> 7, t = blk & 127;
    const int ty  = t >> 3, tx = t & 7;
    const int y0  = ty * TILE_H;
    const int x0  = tx * TILE_W;
    const int tid = threadIdx.x;

    // ---- unit geometry: 4 wide x 2 tall (R7) ----
    const bool act = tid < NUNIT;
    const int  uc  = act ? tid : 0;
    const int  pr  = uc / NU_ROW;
    const int  px  = uc - pr * NU_ROW;
    const int  x   = px * 4;
    const int  r0  = 2 * pr, r1 = r0 + 1;
    int roff0 = (r0 + 1) * S_LDS + x;
    int roff1 = roff0 + S_LDS;
    if (!act) { roff0 = TRASH_OFF + (tid & 3) * 8; roff1 = roff0 + 4; }
    const int e_w  = EDGE_OFF + (tid + 1) * 4;
    const int e_lf = EDGE_OFF + tid * 4 + 2;
    const int e_rt = EDGE_OFF + (tid + 2) * 4;

    const int gy0 = y0 - HALO_Y + r0, gy1 = gy0 + 1;
    const int gx  = x0 - HALO_X + x;
    const bool gx_in = (gx >= 0) && (gx <= WW - 4);
    const bool in0 = act && gx_in && (gy0 >= 0) && (gy0 < HH);
    const bool in1 = act && gx_in && (gy1 >= 0) && (gy1 < HH);
    const int goff0 = in0 ? (gy0 * WW + gx) : 0;
    const int goff1 = in1 ? (gy1 * WW + gx) : 0;
    const bool is_int = act && (r0 >= HALO_Y) && (r1 < HALO_Y + TILE_H) &&
                        (x >= HALO_X) && (x < HALO_X + TILE_W);
    // inner cells (>=10 rows, >=12 cols from the tile edge) are read by NO
    // neighbor's halo and persist in registers -> no coherent store needed.
    const int rel_r = r0 - HALO_Y, rel_x = x - HALO_X;
    const bool is_inner = is_int && (rel_r >= 10) && (rel_r <= 20) &&
                          (rel_x >= 12) && (rel_x <= 48);
    const bool store_seam = is_int && !is_inner;

    // ---- coefficients ONCE: inline gather, R2-verified predicates ----
    const float* cvb = cv_g + b * CV_PER_B;
    const float* chb = ch_g + b * CH_PER_B;
    float ca[4], cm[4], cb[4], h0[5], h1[5];
#pragma unroll
    for (int j = 0; j < 4; ++j) {
        int gxx = gx + j;
        bool gxo = (gxx >= 0) && (gxx < WW);
        bool a_ok = act && (r0 >= 1) && (gy0 >= 1) && (gy0 <= HH - 1) && gxo;
        ca[j] = a_ok ? LAM * cvb[(gy0 - 1) * WW + gxx] : 0.f;
        bool m_ok = act && (gy1 >= 1) && (gy1 <= HH - 1) && gxo;  // r1>=1 always
        cm[j] = m_ok ? LAM * cvb[(gy1 - 1) * WW + gxx] : 0.f;
        bool b_ok = act && (r1 <= RH - 2) && (gy1 + 1 >= 1) && (gy1 + 1 <= HH - 1) && gxo;
        cb[j] = b_ok ? LAM * cvb[gy1 * WW + gxx] : 0.f;
    }
#pragma unroll
    for (int jj = 0; jj < 5; ++jj) {
        int xe = x + jj, gxe = gx + jj;
        bool e_ok = (xe >= 1) && (xe <= RW - 1) && (gxe >= 1) && (gxe < WW);
        bool ok0 = act && e_ok && (gy0 >= 0) && (gy0 < HH);
        h0[jj] = ok0 ? LAM * chb[gy0 * (WW - 1) + (gxe - 1)] : 0.f;
        bool ok1 = act && e_ok && (gy1 >= 0) && (gy1 < HH);
        h1[jj] = ok1 ? LAM * chb[gy1 * (WW - 1) + (gxe - 1)] : 0.f;
    }

    // ---- neighbor flag index (tid<8 -> one of 8 neighbors) ----
    int nbr = -1;
    if (tid < 8) {
        int d  = tid + (tid >= 4 ? 1 : 0);      // 0..8 skipping center(4)
        int dy = d / 3 - 1, dx = d % 3 - 1;
        int ny = ty + dy, nx = tx + dx;
        if (ny >= 0 && ny < 16 && nx >= 0 && nx < 8)
            nbr = (b << 7) + (ny << 3) + nx;
    }

    // ---- superstep-0 raw load (shift added after the min-reduce) ----
    float v0[4] = {0.f, 0.f, 0.f, 0.f}, v1[4] = {0.f, 0.f, 0.f, 0.f};
    const float* ib = initial + b * IMG;
    if (in0) {
        float4 tv = *reinterpret_cast<const float4*>(ib + goff0);
        v0[0] = tv.x; v0[1] = tv.y; v0[2] = tv.z; v0[3] = tv.w;
    }
    if (in1) {
        float4 tv = *reinterpret_cast<const float4*>(ib + goff1);
        v1[0] = tv.x; v1[1] = tv.y; v1[2] = tv.z; v1[3] = tv.w;
    }

    // ---- partial-min reduce (waves 0..3 cover the 256 partials) ----
    {
        float pm = 3.4e38f;
        if (tid < 256) pm = partials[tid];
        for (int off = 32; off > 0; off >>= 1)
            pm = fminf(pm, __shfl_down(pm, off, 64));
        if (tid < 256 && (tid & 63) == 0) sb[0][MIN_SCR + (tid >> 6)] = pm;
    }

    // guard rows + edge sentinels (once; valid across supersteps)
    for (int i = tid; i < S_LDS; i += NTF) {
        sb[0][i] = 0.f; sb[0][(RH + 1) * S_LDS + i] = 0.f;
        sb[1][i] = 0.f; sb[1][(RH + 1) * S_LDS + i] = 0.f;
    }
    if (tid == 0) {
        float4 z{0.f, 0.f, 0.f, 0.f};
        *reinterpret_cast<float4*>(&sb[0][EDGE_OFF]) = z;
        *reinterpret_cast<float4*>(&sb[1][EDGE_OFF]) = z;
        *reinterpret_cast<float4*>(&sb[0][EDGE_OFF + 577 * 4]) = z;
        *reinterpret_cast<float4*>(&sb[1][EDGE_OFF + 577 * 4]) = z;
    }
    __syncthreads();

    const float mm = fminf(fminf(sb[0][MIN_SCR], sb[0][MIN_SCR + 1]),
                           fminf(sb[0][MIN_SCR + 2], sb[0][MIN_SCR + 3]));
    const float shift = (mm <= DEPS_) ? DEPS_ : 0.f;
    if (in0) { v0[0] += shift; v0[1] += shift; v0[2] += shift; v0[3] += shift; }
    if (in1) { v1[0] += shift; v1[1] += shift; v1[2] += shift; v1[3] += shift; }

    *reinterpret_cast<float4*>(&sb[0][roff0]) = float4{v0[0], v0[1], v0[2], v0[3]};
    *reinterpret_cast<float4*>(&sb[0][roff1]) = float4{v1[0], v1[1], v1[2], v1[3]};
    *reinterpret_cast<float4*>(&sb[0][e_w])   = float4{v0[0], v1[0], v0[3], v1[3]};
    __syncthreads();

    for (int k = 0; k < NSS; ++k) {
        if (k > 0) {
            // wait: 8 neighbors must have COMPLETED superstep k-1
            if (nbr >= 0) {
                while (__hip_atomic_load(&flags[nbr], __ATOMIC_RELAXED,
                                         __HIP_MEMORY_SCOPE_AGENT) < (unsigned)k) {}
            }
            __syncthreads();
            asm volatile("" ::: "memory");   // no compiler reordering past spin
            // halo units reload via coherent loads; interior persists
            const float* srcb = ((k & 1) ? bufA : bufB) + b * IMG;
            if (act && !is_int) {
                float2 a0{0.f, 0.f}, b0{0.f, 0.f}, a1{0.f, 0.f}, b1{0.f, 0.f};
                if (in0) { a0 = cohload8(srcb + goff0); b0 = cohload8(srcb + goff0 + 2); }
                if (in1) { a1 = cohload8(srcb + goff1); b1 = cohload8(srcb + goff1 + 2); }
                v0[0] = a0.x; v0[1] = a0.y; v0[2] = b0.x; v0[3] = b0.y;
                v1[0] = a1.x; v1[1] = a1.y; v1[2] = b1.x; v1[3] = b1.y;
                *reinterpret_cast<float4*>(&sb[0][roff0]) =
                    float4{v0[0], v0[1], v0[2], v0[3]};
                *reinterpret_cast<float4*>(&sb[0][roff1]) =
                    float4{v1[0], v1[1], v1[2], v1[3]};
                *reinterpret_cast<float4*>(&sb[0][e_w]) =
                    float4{v0[0], v1[0], v0[3], v1[3]};
            }
            __syncthreads();
        }

        int cur = 0;
        for (int it = 0; it < T_FUSE; ++it) {
            const float* s = sb[cur];
            float2 lfp = *reinterpret_cast<const float2*>(&s[e_lf]);
            float2 rtp = *reinterpret_cast<const float2*>(&s[e_rt]);
            float4 up = *reinterpret_cast<const float4*>(&s[roff0 - S_LDS]);
            float4 dn = *reinterpret_cast<const float4*>(&s[roff1 + S_LDS]);

            float n0[4], n1[4];
            n0[0] = v0[0] - ca[0] * (v0[0] - up.x) + cm[0] * (v1[0] - v0[0])
                          - h0[0] * (v0[0] - lfp.x) + h0[1] * (v0[1] - v0[0]);
            n0[1] = v0[1] - ca[1] * (v0[1] - up.y) + cm[1] * (v1[1] - v0[1])
                          - h0[1] * (v0[1] - v0[0]) + h0[2] * (v0[2] - v0[1]);
            n0[2] = v0[2] - ca[2] * (v0[2] - up.z) + cm[2] * (v1[2] - v0[2])
                          - h0[2] * (v0[2] - v0[1]) + h0[3] * (v0[3] - v0[2]);
            n0[3] = v0[3] - ca[3] * (v0[3] - up.w) + cm[3] * (v1[3] - v0[3])
                          - h0[3] * (v0[3] - v0[2]) + h0[4] * (rtp.x - v0[3]);
            n1[0] = v1[0] - cm[0] * (v1[0] - v0[0]) + cb[0] * (dn.x - v1[0])
                          - h1[0] * (v1[0] - lfp.y) + h1[1] * (v1[1] - v1[0]);
            n1[1] = v1[1] - cm[1] * (v1[1] - v0[1]) + cb[1] * (dn.y - v1[1])
                          - h1[1] * (v1[1] - v1[0]) + h1[2] * (v1[2] - v1[1]);
            n1[2] = v1[2] - cm[2] * (v1[2] - v0[2]) + cb[2] * (dn.z - v1[2])
                          - h1[2] * (v1[2] - v1[1]) + h1[3] * (v1[3] - v1[2]);
            n1[3] = v1[3] - cm[3] * (v1[3] - v0[3]) + cb[3] * (dn.w - v1[3])
                          - h1[3] * (v1[3] - v1[2]) + h1[4] * (rtp.y - v1[3]);

            int nxt = cur ^ 1;
            float* d = sb[nxt];
            *reinterpret_cast<float4*>(&d[roff0]) = float4{n0[0], n0[1], n0[2], n0[3]};
            *reinterpret_cast<float4*>(&d[roff1]) = float4{n1[0], n1[1], n1[2], n1[3]};
            *reinterpret_cast<float4*>(&d[e_w])   = float4{n0[0], n1[0], n0[3], n1[3]};
            v0[0] = n0[0]; v0[1] = n0[1]; v0[2] = n0[2]; v0[3] = n0[3];
            v1[0] = n1[0]; v1[1] = n1[1]; v1[2] = n1[2]; v1[3] = n1[3];
            cur = nxt;
            __syncthreads();
        }
        // T_FUSE even -> final values live in sb[0]; LDS stays valid for k+1.

        if (k == NSS - 1) {
            float* dstb = out_y + b * IMG;
            if (is_int) {
                float4 o0{v0[0] - shift, v0[1] - shift, v0[2] - shift, v0[3] - shift};
                float4 o1{v1[0] - shift, v1[1] - shift, v1[2] - shift, v1[3] - shift};
                *reinterpret_cast<float4*>(dstb + goff0) = o0;
                *reinterpret_cast<float4*>(dstb + goff1) = o1;
            }
        } else {
            float* dstb = ((k & 1) ? bufB : bufA) + b * IMG;
            if (store_seam) {
                cohstore8(dstb + goff0,     v0[0], v0[1]);
                cohstore8(dstb + goff0 + 2, v0[2], v0[3]);
                cohstore8(dstb + goff1,     v1[0], v1[1]);
                cohstore8(dstb + goff1 + 2, v1[2], v1[3]);
            }
            // drain own coherent stores, then barrier orders all before flag
            asm volatile("s_waitcnt vmcnt(0)" ::: "memory");
            __syncthreads();
            if (tid == 0)
                __hip_atomic_store(&flags[blk], (unsigned)(k + 1),
                                   __ATOMIC_RELAXED, __HIP_MEMORY_SCOPE_AGENT);
        }
    }
}

// -------- fallback (round-2 verified, inline gather, 256 threads) --------
template <bool ADD_SHIFT, bool SUB_SHIFT>
__global__ __launch_bounds__(256, 1) void step_fused(
    const float* __restrict__ src, float* __restrict__ dst,
    const float* __restrict__ cv_g, const float* __restrict__ ch_g,
    const float* __restrict__ keyf) {
    __shared__ float sb[2][SSZ];
    const int blk = blockIdx.x;
    const int b = blk >> 7, t = blk & 127;
    const int y0 = (t >> 3) * TILE_H, x0 = (t & 7) * TILE_W;
    const float* cvb = cv_g + b * CV_PER_B;
    const float* chb = ch_g + b * CH_PER_B;
    const float* srcb = src + b * IMG;
    float* dstb = dst + b * IMG;
    float shift = 0.f;
    if (ADD_SHIFT || SUB_SHIFT) shift = (keyf[0] <= DEPS_) ? DEPS_ : 0.f;
    const int tid = threadIdx.x;
    float v[QPT_F][4], cu[QPT_F][4], cd[QPT_F][4], chq[QPT_F][5];
    int roff[QPT_F], rr[QPT_F], xx[QPT_F];
    bool act[QPT_F];
#pragma unroll
    for (int q = 0; q < QPT_F; ++q) {
        int qi = tid + q * 256;
        act[q] = qi < NQUAD;
        int qc = act[q] ? qi : 0;
        int r = qc / NQ_ROW;
        int x = (qc - r * NQ_ROW) * 4;
        rr[q] = r; xx[q] = x;
        roff[q] = (r + 1) * RW + x;
        int gy = y0 - HALO_Y + r, gx = x0 - HALO_X + x;
        bool gy_in = (gy >= 0) && (gy < HH);
#pragma unroll
        for (int j = 0; j < 4; ++j) {
            int gxx = gx + j;
            bool gx_in = (gxx >= 0) && (gxx < WW);
            bool vin = act[q] && gy_in && gx_in;
            float val = vin ? srcb[gy * WW + gxx] : 0.f;
            if (ADD_SHIFT) val += shift;
            v[q][j] = vin ? val : 0.f;
            bool up_ok = act[q] && (r >= 1) && (gy >= 1) && (gy < HH) && gx_in;
            cu[q][j] = up_ok ? LAM * cvb[(gy - 1) * WW + gxx] : 0.f;
            bool dn_ok = act[q] && (r <= RH - 2) && (gy >= 0) && (gy < HH - 1) && gx_in;
            cd[q][j] = dn_ok ? LAM * cvb[gy * WW + gxx] : 0.f;
        }
#pragma unroll
        for (int jj = 0; jj < 5; ++jj) {
            int xe = x + jj, gxe = gx + jj;
            bool ok = act[q] && (xe >= 1) && (xe <= RW - 1) && gy_in &&
                      (gxe >= 1) && (gxe < WW);
            chq[q][jj] = ok ? LAM * chb[gy * (WW - 1) + (gxe - 1)] : 0.f;
        }
    }
    for (int i = tid; i < RW; i += 256) {
        sb[0][i] = 0.f; sb[0][(RH + 1) * RW + i] = 0.f;
        sb[1][i] = 0.f; sb[1][(RH + 1) * RW + i] = 0.f;
    }
#pragma unroll
    for (int q = 0; q < QPT_F; ++q)
        if (act[q])
            *reinterpret_cast<float4*>(&sb[0][roff[q]]) =
                float4{v[q][0], v[q][1], v[q][2], v[q][3]};
    __syncthreads();
    int cur = 0;
    for (int it = 0; it < T_FUSE; ++it) {
        float nv[QPT_F][4];
#pragma unroll
        for (int q = 0; q < QPT_F; ++q) {
            const float* s = sb[cur];
            float4 up = *reinterpret_cast<const float4*>(&s[roff[q] - RW]);
            float4 dn = *reinterpret_cast<const float4*>(&s[roff[q] + RW]);
            float lf = s[roff[q] - 1];
            float rt = s[roff[q] + 4];
            float c0 = v[q][0], c1 = v[q][1], c2 = v[q][2], c3 = v[q][3];
            nv[q][0] = c0 - cu[q][0] * (c0 - up.x) + cd[q][0] * (dn.x - c0)
                          - chq[q][0] * (c0 - lf) + chq[q][1] * (c1 - c0);
            nv[q][1] = c1 - cu[q][1] * (c1 - up.y) + cd[q][1] * (dn.y - c1)
                          - chq[q][1] * (c1 - c0) + chq[q][2] * (c2 - c1);
            nv[q][2] = c2 - cu[q][2] * (c2 - up.z) + cd[q][2] * (dn.z - c2)
                          - chq[q][2] * (c2 - c1) + chq[q][3] * (c3 - c2);
            nv[q][3] = c3 - cu[q][3] * (c3 - up.w) + cd[q][3] * (dn.w - c3)
                          - chq[q][3] * (c3 - c2) + chq[q][4] * (rt - c3);
        }
        int nxt = cur ^ 1;
#pragma unroll
        for (int q = 0; q < QPT_F; ++q) {
            if (act[q])
                *reinterpret_cast<float4*>(&sb[nxt][roff[q]]) =
                    float4{nv[q][0], nv[q][1], nv[q][2], nv[q][3]};
            v[q][0] = nv[q][0]; v[q][1] = nv[q][1];
            v[q][2] = nv[q][2]; v[q][3] = nv[q][3];
        }
        cur = nxt;
        __syncthreads();
    }
#pragma unroll
    for (int q = 0; q < QPT_F; ++q) {
        if (!act[q]) continue;
        int r = rr[q], x = xx[q];
        if (r >= HALO_Y && r < HALO_Y + TILE_H && x >= HALO_X && x < HALO_X + TILE_W) {
            int gy = y0 - HALO_Y + r, gx = x0 - HALO_X + x;
            float4 o{v[q][0], v[q][1], v[q][2], v[q][3]};
            if (SUB_SHIFT) { o.x -= shift; o.y -= shift; o.z -= shift; o.w -= shift; }
            *reinterpret_cast<float4*>(dstb + gy * WW + gx) = o;
        }
    }
}

extern "C" void kernel_launch(void* const* d_in, const int* in_sizes, int n_in,
                              void* d_out, int out_size, void* d_ws, size_t ws_size,
                              hipStream_t stream) {
    const float* guide   = (const float*)d_in[0];
    const float* initial = (const float*)d_in[1];
    float* out    = (float*)d_out;
    float* out_y  = out;
    float* out_cv = out + N_DEPTH;
    float* out_ch = out + N_DEPTH + N_CV;

    float* wsf    = (float*)d_ws;
    float* keyf   = wsf;                       // slot 0 (fallback only)
    float* bufA   = wsf + 64;
    float* bufB   = bufA + N_DEPTH;
    unsigned* flags = (unsigned*)(bufB + N_DEPTH);     // 256
    float* partials = (float*)(flags + 256);           // 256

    const size_t need = (size_t)(64 + 2 * N_DEPTH + 512) * 4;
    const bool fast = ws_size >= need;

    hipLaunchKernelGGL(coeff_min_kernel, dim3(NCO_BLK + 256), dim3(256), 0, stream,
                       guide, initial, out_cv, out_ch, partials, flags);

    if (fast) {
        const float* a0 = initial;
        float* a1 = out_y;
        float* a2 = bufA;
        float* a3 = bufB;
        const float* a4 = out_cv;
        const float* a5 = out_ch;
        const float* a6 = partials;
        unsigned* a7 = flags;
        void* kargs[] = {&a0, &a1, &a2, &a3, &a4, &a5, &a6, &a7};
        hipError_t ce = hipLaunchCooperativeKernel(
            (const void*)diffuse_persist, dim3(256), dim3(NTF), kargs, 0, stream);
        if (ce == hipSuccess) return;
    }

    // fallback: derive shift then R2-verified relaunch loop
    hipLaunchKernelGGL(key_from_partials, dim3(1), dim3(256), 0, stream,
                       partials, keyf);
    float* bufs[2] = {bufA, bufB};
    for (int k = 0; k < NSS; ++k) {
        const float* src = (k == 0) ? initial : bufs[(k + 1) & 1];
        float*       dst = (k == NSS - 1) ? out_y : bufs[k & 1];
        if (k == 0)
            hipLaunchKernelGGL((step_fused<true, false>), dim3(256), dim3(256), 0,
                               stream, src, dst, out_cv, out_ch, keyf);
        else if (k == NSS - 1)
            hipLaunchKernelGGL((step_fused<false, true>), dim3(256), dim3(256), 0,
                               stream, src, dst, out_cv, out_ch, keyf);
        else
            hipLaunchKernelGGL((step_fused<false, false>), dim3(256), dim3(256), 0,
                               stream, src, dst, out_cv, out_ch, keyf);
    }
}

// Round 11
// 442.069 us; speedup vs baseline: 6.6485x; 1.0434x over previous
//
#include <hip/hip_runtime.h>

// Perona-Malik diffusion, 500 iters. Round-15: persistent v5 = v4 with the
// cooperative launch replaced by a REGULAR launch. R14 accounting: persist
// dispatch ~406us but total 461 -> ~50us fixed gap, constant across R12-R14
// regardless of prologue kernel count => hipLaunchCooperativeKernel's fixed
// host-side overhead, not per-launch gaps. diffuse_persist uses no
// cooperative-groups API; it only needs co-residency, which is structural:
// 256 blocks / 256 CUs, 59KB LDS (<160), 9 waves (<32), 64 VGPR -- even a
// 2-blocks-per-CU placement co-resides (118KB, 18 waves). Regular launch is
// therefore safe; sync remains the R12 flag protocol (agent-scope coherent
// ops, no fences). Everything else identical to R14 (461us, absmax exact).

#define HH 512
#define WW 512
#define NB 2
static constexpr float LAM   = 0.24f;
static constexpr float KCOND = 0.03f;
static constexpr float DEPS_ = 0.1f;
static constexpr int IMG      = HH * WW;
static constexpr int N_DEPTH  = NB * IMG;
static constexpr int CV_PER_B = (HH - 1) * WW;
static constexpr int CH_PER_B = HH * (WW - 1);
static constexpr int N_CV     = NB * CV_PER_B;
static constexpr int N_CH     = NB * CH_PER_B;

static constexpr int T_FUSE = 10, NSS = 50;       // 50 x 10 = 500
static constexpr int TILE_W = 64, TILE_H = 32;
static constexpr int HALO_X = 12, HALO_Y = 10;
static constexpr int RW = TILE_W + 2 * HALO_X;    // 88
static constexpr int RH = TILE_H + 2 * HALO_Y;    // 52
static constexpr int NQ_ROW = RW / 4;             // 22
static constexpr int NQUAD  = NQ_ROW * RH;        // 1144 (fallback)
static constexpr int SSZ    = (RH + 2) * RW;      // fallback layout (4752)

// persistent path: 4x2 units, one per thread (R7 geometry)
static constexpr int NU_ROW = RW / 4;              // 22 units per row-pair
static constexpr int NU_COL = RH / 2;              // 26 row-pairs
static constexpr int NUNIT  = NU_ROW * NU_COL;     // 572
static constexpr int NTF    = 576;                 // 9 waves

// LDS layout (floats), per ping-pong buffer (R7):
static constexpr int S_LDS    = 92;
static constexpr int ROWS_SZ  = (RH + 2) * S_LDS;       // 4968
static constexpr int TRASH_OFF = ROWS_SZ;               // 4968
static constexpr int EDGE_OFF = ROWS_SZ + S_LDS;        // 5060 (16B aligned)
static constexpr int EDGE_ENT = 580;                    // entries 0..577 used
static constexpr int BUF_SZ   = EDGE_OFF + EDGE_ENT * 4; // 7380
// scratch for the partial-min broadcast (inside sb[0] trash area, above the
// !act slots which only use TRASH_OFF..TRASH_OFF+31)
static constexpr int MIN_SCR  = TRASH_OFF + 40;

// fallback path (round-2 verified): 256 threads, 5 quads/thread
static constexpr int QPT_F = 5;

// ---- per-access coherent 8B load/store (agent scope, relaxed) ----
__device__ __forceinline__ float2 cohload8(const float* p) {
    unsigned long long u = __hip_atomic_load(
        reinterpret_cast<const unsigned long long*>(p),
        __ATOMIC_RELAXED, __HIP_MEMORY_SCOPE_AGENT);
    union { unsigned long long u; float2 f; } c; c.u = u;
    return c.f;
}
__device__ __forceinline__ void cohstore8(float* p, float a, float b) {
    union { unsigned long long u; float f[2]; } c;
    c.f[0] = a; c.f[1] = b;
    __hip_atomic_store(reinterpret_cast<unsigned long long*>(p), c.u,
                       __ATOMIC_RELAXED, __HIP_MEMORY_SCOPE_AGENT);
}

// coeff (blocks [0, NCO_BLK)) + min-partials (blocks [NCO_BLK, NCO_BLK+256))
static constexpr int NCO_BLK = (N_CV + N_CH + 255) / 256;
__global__ void coeff_min_kernel(const float* __restrict__ g,
                                 const float* __restrict__ ini,
                                 float* __restrict__ cv, float* __restrict__ chh,
                                 float* __restrict__ partials,
                                 unsigned* __restrict__ flags) {
    constexpr float kk = KCOND * KCOND;
    if ((int)blockIdx.x >= NCO_BLK) {
        // ---- partial min over initial (no atomics, no seed needed) ----
        int bid = blockIdx.x - NCO_BLK;
        if (threadIdx.x == 0) flags[bid] = 0u;   // zero the progress flag
        float m = 3.4e38f;
        for (int idx = bid * 256 + threadIdx.x; idx < N_DEPTH; idx += 256 * 256)
            m = fminf(m, ini[idx]);
        for (int off = 32; off > 0; off >>= 1) m = fminf(m, __shfl_down(m, off, 64));
        __shared__ float sm[4];
        int lane = threadIdx.x & 63, wv = threadIdx.x >> 6;
        if (lane == 0) sm[wv] = m;
        __syncthreads();
        if (threadIdx.x == 0)
            partials[bid] = fminf(fminf(sm[0], sm[1]), fminf(sm[2], sm[3]));
        return;
    }
    int idx = blockIdx.x * 256 + threadIdx.x;
    if (idx < N_CV) {
        int b = idx / CV_PER_B;
        int r = idx - b * CV_PER_B;
        int i = r >> 9, j = r & (WW - 1);
        const float* gb = g + b * 3 * IMG + i * WW + j;
        float s = 0.f;
#pragma unroll
        for (int c = 0; c < 3; ++c) s += fabsf(gb[c * IMG + WW] - gb[c * IMG]);
        float m = s / 3.0f;
        cv[idx] = 1.0f / (1.0f + (m * m) / kk);
    } else if (idx < N_CV + N_CH) {
        int t = idx - N_CV;
        int b = t / CH_PER_B;
        int r = t - b * CH_PER_B;
        int i = r / (WW - 1);
        int j = r - i * (WW - 1);
        const float* gb = g + b * 3 * IMG + i * WW + j;
        float s = 0.f;
#pragma unroll
        for (int c = 0; c < 3; ++c) s += fabsf(gb[c * IMG + 1] - gb[c * IMG]);
        float m = s / 3.0f;
        chh[t] = 1.0f / (1.0f + (m * m) / kk);
    }
}

// fallback helper: reduce 256 partials -> keyf (the min of initial)
__global__ void key_from_partials(const float* __restrict__ partials,
                                  float* __restrict__ keyf) {
    float m = partials[threadIdx.x];
    for (int off = 32; off > 0; off >>= 1) m = fminf(m, __shfl_down(m, off, 64));
    __shared__ float sm[4];
    int lane = threadIdx.x & 63, wv = threadIdx.x >> 6;
    if (lane == 0) sm[wv] = m;
    __syncthreads();
    if (threadIdx.x == 0)
        keyf[0] = fminf(fminf(sm[0], sm[1]), fminf(sm[2], sm[3]));
}

// ================= persistent kernel (v5: regular launch) =================
__global__ __launch_bounds__(NTF, 1) void diffuse_persist(
    const float* __restrict__ initial, float* __restrict__ out_y,
    float* __restrict__ bufA, float* __restrict__ bufB,
    const float* __restrict__ cv_g, const float* __restrict__ ch_g,
    const float* __restrict__ partials, unsigned* __restrict__ flags) {
    __shared__ float sb[2][BUF_SZ];
    const int blk = blockIdx.x;
    const int b   = blk >> 7, t = blk & 127;
    const int ty  = t >> 3, tx = t & 7;
    const int y0  = ty * TILE_H;
    const int x0  = tx * TILE_W;
    const int tid = threadIdx.x;

    // ---- unit geometry: 4 wide x 2 tall (R7) ----
    const bool act = tid < NUNIT;
    const int  uc  = act ? tid : 0;
    const int  pr  = uc / NU_ROW;
    const int  px  = uc - pr * NU_ROW;
    const int  x   = px * 4;
    const int  r0  = 2 * pr, r1 = r0 + 1;
    int roff0 = (r0 + 1) * S_LDS + x;
    int roff1 = roff0 + S_LDS;
    if (!act) { roff0 = TRASH_OFF + (tid & 3) * 8; roff1 = roff0 + 4; }
    const int e_w  = EDGE_OFF + (tid + 1) * 4;
    const int e_lf = EDGE_OFF + tid * 4 + 2;
    const int e_rt = EDGE_OFF + (tid + 2) * 4;

    const int gy0 = y0 - HALO_Y + r0, gy1 = gy0 + 1;
    const int gx  = x0 - HALO_X + x;
    const bool gx_in = (gx >= 0) && (gx <= WW - 4);
    const bool in0 = act && gx_in && (gy0 >= 0) && (gy0 < HH);
    const bool in1 = act && gx_in && (gy1 >= 0) && (gy1 < HH);
    const int goff0 = in0 ? (gy0 * WW + gx) : 0;
    const int goff1 = in1 ? (gy1 * WW + gx) : 0;
    const bool is_int = act && (r0 >= HALO_Y) && (r1 < HALO_Y + TILE_H) &&
                        (x >= HALO_X) && (x < HALO_X + TILE_W);
    // inner cells (>=10 rows, >=12 cols from the tile edge) are read by NO
    // neighbor's halo and persist in registers -> no coherent store needed.
    const int rel_r = r0 - HALO_Y, rel_x = x - HALO_X;
    const bool is_inner = is_int && (rel_r >= 10) && (rel_r <= 20) &&
                          (rel_x >= 12) && (rel_x <= 48);
    const bool store_seam = is_int && !is_inner;

    // ---- coefficients ONCE: inline gather, R2-verified predicates ----
    const float* cvb = cv_g + b * CV_PER_B;
    const float* chb = ch_g + b * CH_PER_B;
    float ca[4], cm[4], cb[4], h0[5], h1[5];
#pragma unroll
    for (int j = 0; j < 4; ++j) {
        int gxx = gx + j;
        bool gxo = (gxx >= 0) && (gxx < WW);
        bool a_ok = act && (r0 >= 1) && (gy0 >= 1) && (gy0 <= HH - 1) && gxo;
        ca[j] = a_ok ? LAM * cvb[(gy0 - 1) * WW + gxx] : 0.f;
        bool m_ok = act && (gy1 >= 1) && (gy1 <= HH - 1) && gxo;  // r1>=1 always
        cm[j] = m_ok ? LAM * cvb[(gy1 - 1) * WW + gxx] : 0.f;
        bool b_ok = act && (r1 <= RH - 2) && (gy1 + 1 >= 1) && (gy1 + 1 <= HH - 1) && gxo;
        cb[j] = b_ok ? LAM * cvb[gy1 * WW + gxx] : 0.f;
    }
#pragma unroll
    for (int jj = 0; jj < 5; ++jj) {
        int xe = x + jj, gxe = gx + jj;
        bool e_ok = (xe >= 1) && (xe <= RW - 1) && (gxe >= 1) && (gxe < WW);
        bool ok0 = act && e_ok && (gy0 >= 0) && (gy0 < HH);
        h0[jj] = ok0 ? LAM * chb[gy0 * (WW - 1) + (gxe - 1)] : 0.f;
        bool ok1 = act && e_ok && (gy1 >= 0) && (gy1 < HH);
        h1[jj] = ok1 ? LAM * chb[gy1 * (WW - 1) + (gxe - 1)] : 0.f;
    }

    // ---- neighbor flag index (tid<8 -> one of 8 neighbors) ----
    int nbr = -1;
    if (tid < 8) {
        int d  = tid + (tid >= 4 ? 1 : 0);      // 0..8 skipping center(4)
        int dy = d / 3 - 1, dx = d % 3 - 1;
        int ny = ty + dy, nx = tx + dx;
        if (ny >= 0 && ny < 16 && nx >= 0 && nx < 8)
            nbr = (b << 7) + (ny << 3) + nx;
    }

    // ---- superstep-0 raw load (shift added after the min-reduce) ----
    float v0[4] = {0.f, 0.f, 0.f, 0.f}, v1[4] = {0.f, 0.f, 0.f, 0.f};
    const float* ib = initial + b * IMG;
    if (in0) {
        float4 tv = *reinterpret_cast<const float4*>(ib + goff0);
        v0[0] = tv.x; v0[1] = tv.y; v0[2] = tv.z; v0[3] = tv.w;
    }
    if (in1) {
        float4 tv = *reinterpret_cast<const float4*>(ib + goff1);
        v1[0] = tv.x; v1[1] = tv.y; v1[2] = tv.z; v1[3] = tv.w;
    }

    // ---- partial-min reduce (waves 0..3 cover the 256 partials) ----
    {
        float pm = 3.4e38f;
        if (tid < 256) pm = partials[tid];
        for (int off = 32; off > 0; off >>= 1)
            pm = fminf(pm, __shfl_down(pm, off, 64));
        if (tid < 256 && (tid & 63) == 0) sb[0][MIN_SCR + (tid >> 6)] = pm;
    }

    // guard rows + edge sentinels (once; valid across supersteps)
    for (int i = tid; i < S_LDS; i += NTF) {
        sb[0][i] = 0.f; sb[0][(RH + 1) * S_LDS + i] = 0.f;
        sb[1][i] = 0.f; sb[1][(RH + 1) * S_LDS + i] = 0.f;
    }
    if (tid == 0) {
        float4 z{0.f, 0.f, 0.f, 0.f};
        *reinterpret_cast<float4*>(&sb[0][EDGE_OFF]) = z;
        *reinterpret_cast<float4*>(&sb[1][EDGE_OFF]) = z;
        *reinterpret_cast<float4*>(&sb[0][EDGE_OFF + 577 * 4]) = z;
        *reinterpret_cast<float4*>(&sb[1][EDGE_OFF + 577 * 4]) = z;
    }
    __syncthreads();

    const float mm = fminf(fminf(sb[0][MIN_SCR], sb[0][MIN_SCR + 1]),
                           fminf(sb[0][MIN_SCR + 2], sb[0][MIN_SCR + 3]));
    const float shift = (mm <= DEPS_) ? DEPS_ : 0.f;
    if (in0) { v0[0] += shift; v0[1] += shift; v0[2] += shift; v0[3] += shift; }
    if (in1) { v1[0] += shift; v1[1] += shift; v1[2] += shift; v1[3] += shift; }

    *reinterpret_cast<float4*>(&sb[0][roff0]) = float4{v0[0], v0[1], v0[2], v0[3]};
    *reinterpret_cast<float4*>(&sb[0][roff1]) = float4{v1[0], v1[1], v1[2], v1[3]};
    *reinterpret_cast<float4*>(&sb[0][e_w])   = float4{v0[0], v1[0], v0[3], v1[3]};
    __syncthreads();

    for (int k = 0; k < NSS; ++k) {
        if (k > 0) {
            // wait: 8 neighbors must have COMPLETED superstep k-1
            if (nbr >= 0) {
                while (__hip_atomic_load(&flags[nbr], __ATOMIC_RELAXED,
                                         __HIP_MEMORY_SCOPE_AGENT) < (unsigned)k) {}
            }
            __syncthreads();
            asm volatile("" ::: "memory");   // no compiler reordering past spin
            // halo units reload via coherent loads; interior persists
            const float* srcb = ((k & 1) ? bufA : bufB) + b * IMG;
            if (act && !is_int) {
                float2 a0{0.f, 0.f}, b0{0.f, 0.f}, a1{0.f, 0.f}, b1{0.f, 0.f};
                if (in0) { a0 = cohload8(srcb + goff0); b0 = cohload8(srcb + goff0 + 2); }
                if (in1) { a1 = cohload8(srcb + goff1); b1 = cohload8(srcb + goff1 + 2); }
                v0[0] = a0.x; v0[1] = a0.y; v0[2] = b0.x; v0[3] = b0.y;
                v1[0] = a1.x; v1[1] = a1.y; v1[2] = b1.x; v1[3] = b1.y;
                *reinterpret_cast<float4*>(&sb[0][roff0]) =
                    float4{v0[0], v0[1], v0[2], v0[3]};
                *reinterpret_cast<float4*>(&sb[0][roff1]) =
                    float4{v1[0], v1[1], v1[2], v1[3]};
                *reinterpret_cast<float4*>(&sb[0][e_w]) =
                    float4{v0[0], v1[0], v0[3], v1[3]};
            }
            __syncthreads();
        }

        int cur = 0;
        for (int it = 0; it < T_FUSE; ++it) {
            const float* s = sb[cur];
            float2 lfp = *reinterpret_cast<const float2*>(&s[e_lf]);
            float2 rtp = *reinterpret_cast<const float2*>(&s[e_rt]);
            float4 up = *reinterpret_cast<const float4*>(&s[roff0 - S_LDS]);
            float4 dn = *reinterpret_cast<const float4*>(&s[roff1 + S_LDS]);

            float n0[4], n1[4];
            n0[0] = v0[0] - ca[0] * (v0[0] - up.x) + cm[0] * (v1[0] - v0[0])
                          - h0[0] * (v0[0] - lfp.x) + h0[1] * (v0[1] - v0[0]);
            n0[1] = v0[1] - ca[1] * (v0[1] - up.y) + cm[1] * (v1[1] - v0[1])
                          - h0[1] * (v0[1] - v0[0]) + h0[2] * (v0[2] - v0[1]);
            n0[2] = v0[2] - ca[2] * (v0[2] - up.z) + cm[2] * (v1[2] - v0[2])
                          - h0[2] * (v0[2] - v0[1]) + h0[3] * (v0[3] - v0[2]);
            n0[3] = v0[3] - ca[3] * (v0[3] - up.w) + cm[3] * (v1[3] - v0[3])
                          - h0[3] * (v0[3] - v0[2]) + h0[4] * (rtp.x - v0[3]);
            n1[0] = v1[0] - cm[0] * (v1[0] - v0[0]) + cb[0] * (dn.x - v1[0])
                          - h1[0] * (v1[0] - lfp.y) + h1[1] * (v1[1] - v1[0]);
            n1[1] = v1[1] - cm[1] * (v1[1] - v0[1]) + cb[1] * (dn.y - v1[1])
                          - h1[1] * (v1[1] - v1[0]) + h1[2] * (v1[2] - v1[1]);
            n1[2] = v1[2] - cm[2] * (v1[2] - v0[2]) + cb[2] * (dn.z - v1[2])
                          - h1[2] * (v1[2] - v1[1]) + h1[3] * (v1[3] - v1[2]);
            n1[3] = v1[3] - cm[3] * (v1[3] - v0[3]) + cb[3] * (dn.w - v1[3])
                          - h1[3] * (v1[3] - v1[2]) + h1[4] * (rtp.y - v1[3]);

            int nxt = cur ^ 1;
            float* d = sb[nxt];
            *reinterpret_cast<float4*>(&d[roff0]) = float4{n0[0], n0[1], n0[2], n0[3]};
            *reinterpret_cast<float4*>(&d[roff1]) = float4{n1[0], n1[1], n1[2], n1[3]};
            *reinterpret_cast<float4*>(&d[e_w])   = float4{n0[0], n1[0], n0[3], n1[3]};
            v0[0] = n0[0]; v0[1] = n0[1]; v0[2] = n0[2]; v0[3] = n0[3];
            v1[0] = n1[0]; v1[1] = n1[1]; v1[2] = n1[2]; v1[3] = n1[3];
            cur = nxt;
            __syncthreads();
        }
        // T_FUSE even -> final values live in sb[0]; LDS stays valid for k+1.

        if (k == NSS - 1) {
            float* dstb = out_y + b * IMG;
            if (is_int) {
                float4 o0{v0[0] - shift, v0[1] - shift, v0[2] - shift, v0[3] - shift};
                float4 o1{v1[0] - shift, v1[1] - shift, v1[2] - shift, v1[3] - shift};
                *reinterpret_cast<float4*>(dstb + goff0) = o0;
                *reinterpret_cast<float4*>(dstb + goff1) = o1;
            }
        } else {
            float* dstb = ((k & 1) ? bufB : bufA) + b * IMG;
            if (store_seam) {
                cohstore8(dstb + goff0,     v0[0], v0[1]);
                cohstore8(dstb + goff0 + 2, v0[2], v0[3]);
                cohstore8(dstb + goff1,     v1[0], v1[1]);
                cohstore8(dstb + goff1 + 2, v1[2], v1[3]);
            }
            // drain own coherent stores, then barrier orders all before flag
            asm volatile("s_waitcnt vmcnt(0)" ::: "memory");
            __syncthreads();
            if (tid == 0)
                __hip_atomic_store(&flags[blk], (unsigned)(k + 1),
                                   __ATOMIC_RELAXED, __HIP_MEMORY_SCOPE_AGENT);
        }
    }
}

// -------- fallback (round-2 verified, inline gather, 256 threads) --------
template <bool ADD_SHIFT, bool SUB_SHIFT>
__global__ __launch_bounds__(256, 1) void step_fused(
    const float* __restrict__ src, float* __restrict__ dst,
    const float* __restrict__ cv_g, const float* __restrict__ ch_g,
    const float* __restrict__ keyf) {
    __shared__ float sb[2][SSZ];
    const int blk = blockIdx.x;
    const int b = blk >> 7, t = blk & 127;
    const int y0 = (t >> 3) * TILE_H, x0 = (t & 7) * TILE_W;
    const float* cvb = cv_g + b * CV_PER_B;
    const float* chb = ch_g + b * CH_PER_B;
    const float* srcb = src + b * IMG;
    float* dstb = dst + b * IMG;
    float shift = 0.f;
    if (ADD_SHIFT || SUB_SHIFT) shift = (keyf[0] <= DEPS_) ? DEPS_ : 0.f;
    const int tid = threadIdx.x;
    float v[QPT_F][4], cu[QPT_F][4], cd[QPT_F][4], chq[QPT_F][5];
    int roff[QPT_F], rr[QPT_F], xx[QPT_F];
    bool act[QPT_F];
#pragma unroll
    for (int q = 0; q < QPT_F; ++q) {
        int qi = tid + q * 256;
        act[q] = qi < NQUAD;
        int qc = act[q] ? qi : 0;
        int r = qc / NQ_ROW;
        int x = (qc - r * NQ_ROW) * 4;
        rr[q] = r; xx[q] = x;
        roff[q] = (r + 1) * RW + x;
        int gy = y0 - HALO_Y + r, gx = x0 - HALO_X + x;
        bool gy_in = (gy >= 0) && (gy < HH);
#pragma unroll
        for (int j = 0; j < 4; ++j) {
            int gxx = gx + j;
            bool gx_in = (gxx >= 0) && (gxx < WW);
            bool vin = act[q] && gy_in && gx_in;
            float val = vin ? srcb[gy * WW + gxx] : 0.f;
            if (ADD_SHIFT) val += shift;
            v[q][j] = vin ? val : 0.f;
            bool up_ok = act[q] && (r >= 1) && (gy >= 1) && (gy < HH) && gx_in;
            cu[q][j] = up_ok ? LAM * cvb[(gy - 1) * WW + gxx] : 0.f;
            bool dn_ok = act[q] && (r <= RH - 2) && (gy >= 0) && (gy < HH - 1) && gx_in;
            cd[q][j] = dn_ok ? LAM * cvb[gy * WW + gxx] : 0.f;
        }
#pragma unroll
        for (int jj = 0; jj < 5; ++jj) {
            int xe = x + jj, gxe = gx + jj;
            bool ok = act[q] && (xe >= 1) && (xe <= RW - 1) && gy_in &&
                      (gxe >= 1) && (gxe < WW);
            chq[q][jj] = ok ? LAM * chb[gy * (WW - 1) + (gxe - 1)] : 0.f;
        }
    }
    for (int i = tid; i < RW; i += 256) {
        sb[0][i] = 0.f; sb[0][(RH + 1) * RW + i] = 0.f;
        sb[1][i] = 0.f; sb[1][(RH + 1) * RW + i] = 0.f;
    }
#pragma unroll
    for (int q = 0; q < QPT_F; ++q)
        if (act[q])
            *reinterpret_cast<float4*>(&sb[0][roff[q]]) =
                float4{v[q][0], v[q][1], v[q][2], v[q][3]};
    __syncthreads();
    int cur = 0;
    for (int it = 0; it < T_FUSE; ++it) {
        float nv[QPT_F][4];
#pragma unroll
        for (int q = 0; q < QPT_F; ++q) {
            const float* s = sb[cur];
            float4 up = *reinterpret_cast<const float4*>(&s[roff[q] - RW]);
            float4 dn = *reinterpret_cast<const float4*>(&s[roff[q] + RW]);
            float lf = s[roff[q] - 1];
            float rt = s[roff[q] + 4];
            float c0 = v[q][0], c1 = v[q][1], c2 = v[q][2], c3 = v[q][3];
            nv[q][0] = c0 - cu[q][0] * (c0 - up.x) + cd[q][0] * (dn.x - c0)
                          - chq[q][0] * (c0 - lf) + chq[q][1] * (c1 - c0);
            nv[q][1] = c1 - cu[q][1] * (c1 - up.y) + cd[q][1] * (dn.y - c1)
                          - chq[q][1] * (c1 - c0) + chq[q][2] * (c2 - c1);
            nv[q][2] = c2 - cu[q][2] * (c2 - up.z) + cd[q][2] * (dn.z - c2)
                          - chq[q][2] * (c2 - c1) + chq[q][3] * (c3 - c2);
            nv[q][3] = c3 - cu[q][3] * (c3 - up.w) + cd[q][3] * (dn.w - c3)
                          - chq[q][3] * (c3 - c2) + chq[q][4] * (rt - c3);
        }
        int nxt = cur ^ 1;
#pragma unroll
        for (int q = 0; q < QPT_F; ++q) {
            if (act[q])
                *reinterpret_cast<float4*>(&sb[nxt][roff[q]]) =
                    float4{nv[q][0], nv[q][1], nv[q][2], nv[q][3]};
            v[q][0] = nv[q][0]; v[q][1] = nv[q][1];
            v[q][2] = nv[q][2]; v[q][3] = nv[q][3];
        }
        cur = nxt;
        __syncthreads();
    }
#pragma unroll
    for (int q = 0; q < QPT_F; ++q) {
        if (!act[q]) continue;
        int r = rr[q], x = xx[q];
        if (r >= HALO_Y && r < HALO_Y + TILE_H && x >= HALO_X && x < HALO_X + TILE_W) {
            int gy = y0 - HALO_Y + r, gx = x0 - HALO_X + x;
            float4 o{v[q][0], v[q][1], v[q][2], v[q][3]};
            if (SUB_SHIFT) { o.x -= shift; o.y -= shift; o.z -= shift; o.w -= shift; }
            *reinterpret_cast<float4*>(dstb + gy * WW + gx) = o;
        }
    }
}

extern "C" void kernel_launch(void* const* d_in, const int* in_sizes, int n_in,
                              void* d_out, int out_size, void* d_ws, size_t ws_size,
                              hipStream_t stream) {
    const float* guide   = (const float*)d_in[0];
    const float* initial = (const float*)d_in[1];
    float* out    = (float*)d_out;
    float* out_y  = out;
    float* out_cv = out + N_DEPTH;
    float* out_ch = out + N_DEPTH + N_CV;

    float* wsf    = (float*)d_ws;
    float* keyf   = wsf;                       // slot 0 (fallback only)
    float* bufA   = wsf + 64;
    float* bufB   = bufA + N_DEPTH;
    unsigned* flags = (unsigned*)(bufB + N_DEPTH);     // 256
    float* partials = (float*)(flags + 256);           // 256

    const size_t need = (size_t)(64 + 2 * N_DEPTH + 512) * 4;
    const bool fast = ws_size >= need;

    hipLaunchKernelGGL(coeff_min_kernel, dim3(NCO_BLK + 256), dim3(256), 0, stream,
                       guide, initial, out_cv, out_ch, partials, flags);

    if (fast) {
        // Regular launch: kernel uses no cooperative-groups API; co-residency
        // is structural (256 blocks <= 256 CUs; 59KB LDS, 9 waves, 64 VGPR --
        // even 2 blocks/CU co-resides). Avoids hipLaunchCooperativeKernel's
        // fixed host-side overhead (~50us gap observed R12-R14).
        hipLaunchKernelGGL(diffuse_persist, dim3(256), dim3(NTF), 0, stream,
                           initial, out_y, bufA, bufB, out_cv, out_ch,
                           partials, flags);
        return;
    }

    // fallback: derive shift then R2-verified relaunch loop
    hipLaunchKernelGGL(key_from_partials, dim3(1), dim3(256), 0, stream,
                       partials, keyf);
    float* bufs[2] = {bufA, bufB};
    for (int k = 0; k < NSS; ++k) {
        const float* src = (k == 0) ? initial : bufs[(k + 1) & 1];
        float*       dst = (k == NSS - 1) ? out_y : bufs[k & 1];
        if (k == 0)
            hipLaunchKernelGGL((step_fused<true, false>), dim3(256), dim3(256), 0,
                               stream, src, dst, out_cv, out_ch, keyf);
        else if (k == NSS - 1)
            hipLaunchKernelGGL((step_fused<false, true>), dim3(256), dim3(256), 0,
                               stream, src, dst, out_cv, out_ch, keyf);
        else
            hipLaunchKernelGGL((step_fused<false, false>), dim3(256), dim3(256), 0,
                               stream, src, dst, out_cv, out_ch, keyf);
    }
}

// Round 12
// 439.403 us; speedup vs baseline: 6.6889x; 1.0061x over previous
//
#include <hip/hip_runtime.h>

// Perona-Malik diffusion, 500 iters. Round-16: persistent v6 (sync-path cuts).
// R15 landed regular launch (442us; persist ~405 = 250 compute + 150 sync).
// This round shaves the per-superstep sync critical path, bit-identically:
//  (1) seam cohstores FUSED into iteration 10 (issued when nn is computed;
//      MALL latency overlaps the last iter's LDS writes, not serial after);
//  (2) distributed targeted spin: every halo unit has exactly ONE producer
//      tile (quads are 4-aligned in x / 2-aligned in y vs 64x32 tiles, so
//      units never straddle tile boundaries); each reloading thread spins on
//      flags[producer] itself -- deletes the tid<8 proxy spin + one barrier;
//  (3) the it==9 in-loop barrier dropped: nothing reads LDS between iter-10's
//      per-thread-owned writes and the next superstep's reload barrier.
// Out-of-image halo units stay 0 without re-zeroing (all-zero coeffs fix
// their value) -> skipping their reset is bit-identical.
// Everything else identical to R15.

#define HH 512
#define WW 512
#define NB 2
static constexpr float LAM   = 0.24f;
static constexpr float KCOND = 0.03f;
static constexpr float DEPS_ = 0.1f;
static constexpr int IMG      = HH * WW;
static constexpr int N_DEPTH  = NB * IMG;
static constexpr int CV_PER_B = (HH - 1) * WW;
static constexpr int CH_PER_B = HH * (WW - 1);
static constexpr int N_CV     = NB * CV_PER_B;
static constexpr int N_CH     = NB * CH_PER_B;

static constexpr int T_FUSE = 10, NSS = 50;       // 50 x 10 = 500
static constexpr int TILE_W = 64, TILE_H = 32;
static constexpr int HALO_X = 12, HALO_Y = 10;
static constexpr int RW = TILE_W + 2 * HALO_X;    // 88
static constexpr int RH = TILE_H + 2 * HALO_Y;    // 52
static constexpr int NQ_ROW = RW / 4;             // 22
static constexpr int NQUAD  = NQ_ROW * RH;        // 1144 (fallback)
static constexpr int SSZ    = (RH + 2) * RW;      // fallback layout (4752)

// persistent path: 4x2 units, one per thread (R7 geometry)
static constexpr int NU_ROW = RW / 4;              // 22 units per row-pair
static constexpr int NU_COL = RH / 2;              // 26 row-pairs
static constexpr int NUNIT  = NU_ROW * NU_COL;     // 572
static constexpr int NTF    = 576;                 // 9 waves

// LDS layout (floats), per ping-pong buffer (R7):
static constexpr int S_LDS    = 92;
static constexpr int ROWS_SZ  = (RH + 2) * S_LDS;       // 4968
static constexpr int TRASH_OFF = ROWS_SZ;               // 4968
static constexpr int EDGE_OFF = ROWS_SZ + S_LDS;        // 5060 (16B aligned)
static constexpr int EDGE_ENT = 580;                    // entries 0..577 used
static constexpr int BUF_SZ   = EDGE_OFF + EDGE_ENT * 4; // 7380
// scratch for the partial-min broadcast (inside sb[0] trash area, above the
// !act slots which only use TRASH_OFF..TRASH_OFF+31)
static constexpr int MIN_SCR  = TRASH_OFF + 40;

// fallback path (round-2 verified): 256 threads, 5 quads/thread
static constexpr int QPT_F = 5;

// ---- per-access coherent 8B load/store (agent scope, relaxed) ----
__device__ __forceinline__ float2 cohload8(const float* p) {
    unsigned long long u = __hip_atomic_load(
        reinterpret_cast<const unsigned long long*>(p),
        __ATOMIC_RELAXED, __HIP_MEMORY_SCOPE_AGENT);
    union { unsigned long long u; float2 f; } c; c.u = u;
    return c.f;
}
__device__ __forceinline__ void cohstore8(float* p, float a, float b) {
    union { unsigned long long u; float f[2]; } c;
    c.f[0] = a; c.f[1] = b;
    __hip_atomic_store(reinterpret_cast<unsigned long long*>(p), c.u,
                       __ATOMIC_RELAXED, __HIP_MEMORY_SCOPE_AGENT);
}

// coeff (blocks [0, NCO_BLK)) + min-partials (blocks [NCO_BLK, NCO_BLK+256))
static constexpr int NCO_BLK = (N_CV + N_CH + 255) / 256;
__global__ void coeff_min_kernel(const float* __restrict__ g,
                                 const float* __restrict__ ini,
                                 float* __restrict__ cv, float* __restrict__ chh,
                                 float* __restrict__ partials,
                                 unsigned* __restrict__ flags) {
    constexpr float kk = KCOND * KCOND;
    if ((int)blockIdx.x >= NCO_BLK) {
        // ---- partial min over initial (no atomics, no seed needed) ----
        int bid = blockIdx.x - NCO_BLK;
        if (threadIdx.x == 0) flags[bid] = 0u;   // zero the progress flag
        float m = 3.4e38f;
        for (int idx = bid * 256 + threadIdx.x; idx < N_DEPTH; idx += 256 * 256)
            m = fminf(m, ini[idx]);
        for (int off = 32; off > 0; off >>= 1) m = fminf(m, __shfl_down(m, off, 64));
        __shared__ float sm[4];
        int lane = threadIdx.x & 63, wv = threadIdx.x >> 6;
        if (lane == 0) sm[wv] = m;
        __syncthreads();
        if (threadIdx.x == 0)
            partials[bid] = fminf(fminf(sm[0], sm[1]), fminf(sm[2], sm[3]));
        return;
    }
    int idx = blockIdx.x * 256 + threadIdx.x;
    if (idx < N_CV) {
        int b = idx / CV_PER_B;
        int r = idx - b * CV_PER_B;
        int i = r >> 9, j = r & (WW - 1);
        const float* gb = g + b * 3 * IMG + i * WW + j;
        float s = 0.f;
#pragma unroll
        for (int c = 0; c < 3; ++c) s += fabsf(gb[c * IMG + WW] - gb[c * IMG]);
        float m = s / 3.0f;
        cv[idx] = 1.0f / (1.0f + (m * m) / kk);
    } else if (idx < N_CV + N_CH) {
        int t = idx - N_CV;
        int b = t / CH_PER_B;
        int r = t - b * CH_PER_B;
        int i = r / (WW - 1);
        int j = r - i * (WW - 1);
        const float* gb = g + b * 3 * IMG + i * WW + j;
        float s = 0.f;
#pragma unroll
        for (int c = 0; c < 3; ++c) s += fabsf(gb[c * IMG + 1] - gb[c * IMG]);
        float m = s / 3.0f;
        chh[t] = 1.0f / (1.0f + (m * m) / kk);
    }
}

// fallback helper: reduce 256 partials -> keyf (the min of initial)
__global__ void key_from_partials(const float* __restrict__ partials,
                                  float* __restrict__ keyf) {
    float m = partials[threadIdx.x];
    for (int off = 32; off > 0; off >>= 1) m = fminf(m, __shfl_down(m, off, 64));
    __shared__ float sm[4];
    int lane = threadIdx.x & 63, wv = threadIdx.x >> 6;
    if (lane == 0) sm[wv] = m;
    __syncthreads();
    if (threadIdx.x == 0)
        keyf[0] = fminf(fminf(sm[0], sm[1]), fminf(sm[2], sm[3]));
}

// ================= persistent kernel (v6) =================
__global__ __launch_bounds__(NTF, 1) void diffuse_persist(
    const float* __restrict__ initial, float* __restrict__ out_y,
    float* __restrict__ bufA, float* __restrict__ bufB,
    const float* __restrict__ cv_g, const float* __restrict__ ch_g,
    const float* __restrict__ partials, unsigned* __restrict__ flags) {
    __shared__ float sb[2][BUF_SZ];
    const int blk = blockIdx.x;
    const int b   = blk >> 7, t = blk & 127;
    const int ty  = t >> 3, tx = t & 7;
    const int y0  = ty * TILE_H;
    const int x0  = tx * TILE_W;
    const int tid = threadIdx.x;

    // ---- unit geometry: 4 wide x 2 tall (R7) ----
    const bool act = tid < NUNIT;
    const int  uc  = act ? tid : 0;
    const int  pr  = uc / NU_ROW;
    const int  px  = uc - pr * NU_ROW;
    const int  x   = px * 4;
    const int  r0  = 2 * pr, r1 = r0 + 1;
    int roff0 = (r0 + 1) * S_LDS + x;
    int roff1 = roff0 + S_LDS;
    if (!act) { roff0 = TRASH_OFF + (tid & 3) * 8; roff1 = roff0 + 4; }
    const int e_w  = EDGE_OFF + (tid + 1) * 4;
    const int e_lf = EDGE_OFF + tid * 4 + 2;
    const int e_rt = EDGE_OFF + (tid + 2) * 4;

    const int gy0 = y0 - HALO_Y + r0, gy1 = gy0 + 1;
    const int gx  = x0 - HALO_X + x;
    const bool gx_in = (gx >= 0) && (gx <= WW - 4);
    const bool in0 = act && gx_in && (gy0 >= 0) && (gy0 < HH);
    const bool in1 = act && gx_in && (gy1 >= 0) && (gy1 < HH);
    const int goff0 = in0 ? (gy0 * WW + gx) : 0;
    const int goff1 = in1 ? (gy1 * WW + gx) : 0;
    const bool is_int = act && (r0 >= HALO_Y) && (r1 < HALO_Y + TILE_H) &&
                        (x >= HALO_X) && (x < HALO_X + TILE_W);
    // inner cells (>=10 rows, >=12 cols from the tile edge) are read by NO
    // neighbor's halo and persist in registers -> no coherent store needed.
    const int rel_r = r0 - HALO_Y, rel_x = x - HALO_X;
    const bool is_inner = is_int && (rel_r >= 10) && (rel_r <= 20) &&
                          (rel_x >= 12) && (rel_x <= 48);
    const bool store_seam = is_int && !is_inner;

    // halo units that reload each superstep, and their (unique) producer
    // block: quads are 4-aligned in x (64-wide tiles) and 2-aligned in y
    // (even halo/tile heights), so a unit never straddles tile boundaries.
    const bool reload = act && !is_int && (in0 || in1);
    int pblk = 0;
    if (reload) {
        int gyy = in0 ? gy0 : gy1;
        pblk = (b << 7) + ((gyy >> 5) << 3) + (gx >> 6);
    }

    // ---- coefficients ONCE: inline gather, R2-verified predicates ----
    const float* cvb = cv_g + b * CV_PER_B;
    const float* chb = ch_g + b * CH_PER_B;
    float ca[4], cm[4], cb[4], h0[5], h1[5];
#pragma unroll
    for (int j = 0; j < 4; ++j) {
        int gxx = gx + j;
        bool gxo = (gxx >= 0) && (gxx < WW);
        bool a_ok = act && (r0 >= 1) && (gy0 >= 1) && (gy0 <= HH - 1) && gxo;
        ca[j] = a_ok ? LAM * cvb[(gy0 - 1) * WW + gxx] : 0.f;
        bool m_ok = act && (gy1 >= 1) && (gy1 <= HH - 1) && gxo;  // r1>=1 always
        cm[j] = m_ok ? LAM * cvb[(gy1 - 1) * WW + gxx] : 0.f;
        bool b_ok = act && (r1 <= RH - 2) && (gy1 + 1 >= 1) && (gy1 + 1 <= HH - 1) && gxo;
        cb[j] = b_ok ? LAM * cvb[gy1 * WW + gxx] : 0.f;
    }
#pragma unroll
    for (int jj = 0; jj < 5; ++jj) {
        int xe = x + jj, gxe = gx + jj;
        bool e_ok = (xe >= 1) && (xe <= RW - 1) && (gxe >= 1) && (gxe < WW);
        bool ok0 = act && e_ok && (gy0 >= 0) && (gy0 < HH);
        h0[jj] = ok0 ? LAM * chb[gy0 * (WW - 1) + (gxe - 1)] : 0.f;
        bool ok1 = act && e_ok && (gy1 >= 0) && (gy1 < HH);
        h1[jj] = ok1 ? LAM * chb[gy1 * (WW - 1) + (gxe - 1)] : 0.f;
    }

    // ---- superstep-0 raw load (shift added after the min-reduce) ----
    float v0[4] = {0.f, 0.f, 0.f, 0.f}, v1[4] = {0.f, 0.f, 0.f, 0.f};
    const float* ib = initial + b * IMG;
    if (in0) {
        float4 tv = *reinterpret_cast<const float4*>(ib + goff0);
        v0[0] = tv.x; v0[1] = tv.y; v0[2] = tv.z; v0[3] = tv.w;
    }
    if (in1) {
        float4 tv = *reinterpret_cast<const float4*>(ib + goff1);
        v1[0] = tv.x; v1[1] = tv.y; v1[2] = tv.z; v1[3] = tv.w;
    }

    // ---- partial-min reduce (waves 0..3 cover the 256 partials) ----
    {
        float pm = 3.4e38f;
        if (tid < 256) pm = partials[tid];
        for (int off = 32; off > 0; off >>= 1)
            pm = fminf(pm, __shfl_down(pm, off, 64));
        if (tid < 256 && (tid & 63) == 0) sb[0][MIN_SCR + (tid >> 6)] = pm;
    }

    // guard rows + edge sentinels (once; valid across supersteps)
    for (int i = tid; i < S_LDS; i += NTF) {
        sb[0][i] = 0.f; sb[0][(RH + 1) * S_LDS + i] = 0.f;
        sb[1][i] = 0.f; sb[1][(RH + 1) * S_LDS + i] = 0.f;
    }
    if (tid == 0) {
        float4 z{0.f, 0.f, 0.f, 0.f};
        *reinterpret_cast<float4*>(&sb[0][EDGE_OFF]) = z;
        *reinterpret_cast<float4*>(&sb[1][EDGE_OFF]) = z;
        *reinterpret_cast<float4*>(&sb[0][EDGE_OFF + 577 * 4]) = z;
        *reinterpret_cast<float4*>(&sb[1][EDGE_OFF + 577 * 4]) = z;
    }
    __syncthreads();

    const float mm = fminf(fminf(sb[0][MIN_SCR], sb[0][MIN_SCR + 1]),
                           fminf(sb[0][MIN_SCR + 2], sb[0][MIN_SCR + 3]));
    const float shift = (mm <= DEPS_) ? DEPS_ : 0.f;
    if (in0) { v0[0] += shift; v0[1] += shift; v0[2] += shift; v0[3] += shift; }
    if (in1) { v1[0] += shift; v1[1] += shift; v1[2] += shift; v1[3] += shift; }

    *reinterpret_cast<float4*>(&sb[0][roff0]) = float4{v0[0], v0[1], v0[2], v0[3]};
    *reinterpret_cast<float4*>(&sb[0][roff1]) = float4{v1[0], v1[1], v1[2], v1[3]};
    *reinterpret_cast<float4*>(&sb[0][e_w])   = float4{v0[0], v1[0], v0[3], v1[3]};
    __syncthreads();

    for (int k = 0; k < NSS; ++k) {
        if (k > 0) {
            // each reloading halo thread waits for ITS producer, then loads
            if (reload) {
                while (__hip_atomic_load(&flags[pblk], __ATOMIC_RELAXED,
                                         __HIP_MEMORY_SCOPE_AGENT) < (unsigned)k) {}
                asm volatile("" ::: "memory");
                const float* srcb = ((k & 1) ? bufA : bufB) + b * IMG;
                float2 a0{0.f, 0.f}, b0{0.f, 0.f}, a1{0.f, 0.f}, b1{0.f, 0.f};
                if (in0) { a0 = cohload8(srcb + goff0); b0 = cohload8(srcb + goff0 + 2); }
                if (in1) { a1 = cohload8(srcb + goff1); b1 = cohload8(srcb + goff1 + 2); }
                v0[0] = a0.x; v0[1] = a0.y; v0[2] = b0.x; v0[3] = b0.y;
                v1[0] = a1.x; v1[1] = a1.y; v1[2] = b1.x; v1[3] = b1.y;
                *reinterpret_cast<float4*>(&sb[0][roff0]) =
                    float4{v0[0], v0[1], v0[2], v0[3]};
                *reinterpret_cast<float4*>(&sb[0][roff1]) =
                    float4{v1[0], v1[1], v1[2], v1[3]};
                *reinterpret_cast<float4*>(&sb[0][e_w]) =
                    float4{v0[0], v1[0], v0[3], v1[3]};
            }
            __syncthreads();
        }

        const bool do_seam = store_seam && (k < NSS - 1);
        float* dst_sb = ((k & 1) ? bufB : bufA) + b * IMG;

        int cur = 0;
        for (int it = 0; it < T_FUSE; ++it) {
            const float* s = sb[cur];
            float2 lfp = *reinterpret_cast<const float2*>(&s[e_lf]);
            float2 rtp = *reinterpret_cast<const float2*>(&s[e_rt]);
            float4 up = *reinterpret_cast<const float4*>(&s[roff0 - S_LDS]);
            float4 dn = *reinterpret_cast<const float4*>(&s[roff1 + S_LDS]);

            float n0[4], n1[4];
            n0[0] = v0[0] - ca[0] * (v0[0] - up.x) + cm[0] * (v1[0] - v0[0])
                          - h0[0] * (v0[0] - lfp.x) + h0[1] * (v0[1] - v0[0]);
            n0[1] = v0[1] - ca[1] * (v0[1] - up.y) + cm[1] * (v1[1] - v0[1])
                          - h0[1] * (v0[1] - v0[0]) + h0[2] * (v0[2] - v0[1]);
            n0[2] = v0[2] - ca[2] * (v0[2] - up.z) + cm[2] * (v1[2] - v0[2])
                          - h0[2] * (v0[2] - v0[1]) + h0[3] * (v0[3] - v0[2]);
            n0[3] = v0[3] - ca[3] * (v0[3] - up.w) + cm[3] * (v1[3] - v0[3])
                          - h0[3] * (v0[3] - v0[2]) + h0[4] * (rtp.x - v0[3]);
            n1[0] = v1[0] - cm[0] * (v1[0] - v0[0]) + cb[0] * (dn.x - v1[0])
                          - h1[0] * (v1[0] - lfp.y) + h1[1] * (v1[1] - v1[0]);
            n1[1] = v1[1] - cm[1] * (v1[1] - v0[1]) + cb[1] * (dn.y - v1[1])
                          - h1[1] * (v1[1] - v1[0]) + h1[2] * (v1[2] - v1[1]);
            n1[2] = v1[2] - cm[2] * (v1[2] - v0[2]) + cb[2] * (dn.z - v1[2])
                          - h1[2] * (v1[2] - v1[1]) + h1[3] * (v1[3] - v1[2]);
            n1[3] = v1[3] - cm[3] * (v1[3] - v0[3]) + cb[3] * (dn.w - v1[3])
                          - h1[3] * (v1[3] - v1[2]) + h1[4] * (rtp.y - v1[3]);

            // last iteration: issue seam stores NOW so their MALL latency
            // overlaps the LDS writes + drain below (same values as before)
            if (it == T_FUSE - 1 && do_seam) {
                cohstore8(dst_sb + goff0,     n0[0], n0[1]);
                cohstore8(dst_sb + goff0 + 2, n0[2], n0[3]);
                cohstore8(dst_sb + goff1,     n1[0], n1[1]);
                cohstore8(dst_sb + goff1 + 2, n1[2], n1[3]);
            }

            int nxt = cur ^ 1;
            float* d = sb[nxt];
            *reinterpret_cast<float4*>(&d[roff0]) = float4{n0[0], n0[1], n0[2], n0[3]};
            *reinterpret_cast<float4*>(&d[roff1]) = float4{n1[0], n1[1], n1[2], n1[3]};
            *reinterpret_cast<float4*>(&d[e_w])   = float4{n0[0], n1[0], n0[3], n1[3]};
            v0[0] = n0[0]; v0[1] = n0[1]; v0[2] = n0[2]; v0[3] = n0[3];
            v1[0] = n1[0]; v1[1] = n1[1]; v1[2] = n1[2]; v1[3] = n1[3];
            cur = nxt;
            // the it==T_FUSE-1 barrier is subsumed by the post-drain barrier
            // below (k<NSS-1) or unnecessary (k==NSS-1: only register reads
            // follow); nothing reads LDS until the next reload barrier.
            if (it != T_FUSE - 1) __syncthreads();
        }
        // T_FUSE even -> final values live in sb[0]; LDS stays valid for k+1.

        if (k == NSS - 1) {
            float* dstb = out_y + b * IMG;
            if (is_int) {
                float4 o0{v0[0] - shift, v0[1] - shift, v0[2] - shift, v0[3] - shift};
                float4 o1{v1[0] - shift, v1[1] - shift, v1[2] - shift, v1[3] - shift};
                *reinterpret_cast<float4*>(dstb + goff0) = o0;
                *reinterpret_cast<float4*>(dstb + goff1) = o1;
            }
        } else {
            // drain own coherent stores (issued during iter 10), then the
            // barrier orders ALL threads' stores before tid0 posts the flag
            asm volatile("s_waitcnt vmcnt(0)" ::: "memory");
            __syncthreads();
            if (tid == 0)
                __hip_atomic_store(&flags[blk], (unsigned)(k + 1),
                                   __ATOMIC_RELAXED, __HIP_MEMORY_SCOPE_AGENT);
        }
    }
}

// -------- fallback (round-2 verified, inline gather, 256 threads) --------
template <bool ADD_SHIFT, bool SUB_SHIFT>
__global__ __launch_bounds__(256, 1) void step_fused(
    const float* __restrict__ src, float* __restrict__ dst,
    const float* __restrict__ cv_g, const float* __restrict__ ch_g,
    const float* __restrict__ keyf) {
    __shared__ float sb[2][SSZ];
    const int blk = blockIdx.x;
    const int b = blk >> 7, t = blk & 127;
    const int y0 = (t >> 3) * TILE_H, x0 = (t & 7) * TILE_W;
    const float* cvb = cv_g + b * CV_PER_B;
    const float* chb = ch_g + b * CH_PER_B;
    const float* srcb = src + b * IMG;
    float* dstb = dst + b * IMG;
    float shift = 0.f;
    if (ADD_SHIFT || SUB_SHIFT) shift = (keyf[0] <= DEPS_) ? DEPS_ : 0.f;
    const int tid = threadIdx.x;
    float v[QPT_F][4], cu[QPT_F][4], cd[QPT_F][4], chq[QPT_F][5];
    int roff[QPT_F], rr[QPT_F], xx[QPT_F];
    bool act[QPT_F];
#pragma unroll
    for (int q = 0; q < QPT_F; ++q) {
        int qi = tid + q * 256;
        act[q] = qi < NQUAD;
        int qc = act[q] ? qi : 0;
        int r = qc / NQ_ROW;
        int x = (qc - r * NQ_ROW) * 4;
        rr[q] = r; xx[q] = x;
        roff[q] = (r + 1) * RW + x;
        int gy = y0 - HALO_Y + r, gx = x0 - HALO_X + x;
        bool gy_in = (gy >= 0) && (gy < HH);
#pragma unroll
        for (int j = 0; j < 4; ++j) {
            int gxx = gx + j;
            bool gx_in = (gxx >= 0) && (gxx < WW);
            bool vin = act[q] && gy_in && gx_in;
            float val = vin ? srcb[gy * WW + gxx] : 0.f;
            if (ADD_SHIFT) val += shift;
            v[q][j] = vin ? val : 0.f;
            bool up_ok = act[q] && (r >= 1) && (gy >= 1) && (gy < HH) && gx_in;
            cu[q][j] = up_ok ? LAM * cvb[(gy - 1) * WW + gxx] : 0.f;
            bool dn_ok = act[q] && (r <= RH - 2) && (gy >= 0) && (gy < HH - 1) && gx_in;
            cd[q][j] = dn_ok ? LAM * cvb[gy * WW + gxx] : 0.f;
        }
#pragma unroll
        for (int jj = 0; jj < 5; ++jj) {
            int xe = x + jj, gxe = gx + jj;
            bool ok = act[q] && (xe >= 1) && (xe <= RW - 1) && gy_in &&
                      (gxe >= 1) && (gxe < WW);
            chq[q][jj] = ok ? LAM * chb[gy * (WW - 1) + (gxe - 1)] : 0.f;
        }
    }
    for (int i = tid; i < RW; i += 256) {
        sb[0][i] = 0.f; sb[0][(RH + 1) * RW + i] = 0.f;
        sb[1][i] = 0.f; sb[1][(RH + 1) * RW + i] = 0.f;
    }
#pragma unroll
    for (int q = 0; q < QPT_F; ++q)
        if (act[q])
            *reinterpret_cast<float4*>(&sb[0][roff[q]]) =
                float4{v[q][0], v[q][1], v[q][2], v[q][3]};
    __syncthreads();
    int cur = 0;
    for (int it = 0; it < T_FUSE; ++it) {
        float nv[QPT_F][4];
#pragma unroll
        for (int q = 0; q < QPT_F; ++q) {
            const float* s = sb[cur];
            float4 up = *reinterpret_cast<const float4*>(&s[roff[q] - RW]);
            float4 dn = *reinterpret_cast<const float4*>(&s[roff[q] + RW]);
            float lf = s[roff[q] - 1];
            float rt = s[roff[q] + 4];
            float c0 = v[q][0], c1 = v[q][1], c2 = v[q][2], c3 = v[q][3];
            nv[q][0] = c0 - cu[q][0] * (c0 - up.x) + cd[q][0] * (dn.x - c0)
                          - chq[q][0] * (c0 - lf) + chq[q][1] * (c1 - c0);
            nv[q][1] = c1 - cu[q][1] * (c1 - up.y) + cd[q][1] * (dn.y - c1)
                          - chq[q][1] * (c1 - c0) + chq[q][2] * (c2 - c1);
            nv[q][2] = c2 - cu[q][2] * (c2 - up.z) + cd[q][2] * (dn.z - c2)
                          - chq[q][2] * (c2 - c1) + chq[q][3] * (c3 - c2);
            nv[q][3] = c3 - cu[q][3] * (c3 - up.w) + cd[q][3] * (dn.w - c3)
                          - chq[q][3] * (c3 - c2) + chq[q][4] * (rt - c3);
        }
        int nxt = cur ^ 1;
#pragma unroll
        for (int q = 0; q < QPT_F; ++q) {
            if (act[q])
                *reinterpret_cast<float4*>(&sb[nxt][roff[q]]) =
                    float4{nv[q][0], nv[q][1], nv[q][2], nv[q][3]};
            v[q][0] = nv[q][0]; v[q][1] = nv[q][1];
            v[q][2] = nv[q][2]; v[q][3] = nv[q][3];
        }
        cur = nxt;
        __syncthreads();
    }
#pragma unroll
    for (int q = 0; q < QPT_F; ++q) {
        if (!act[q]) continue;
        int r = rr[q], x = xx[q];
        if (r >= HALO_Y && r < HALO_Y + TILE_H && x >= HALO_X && x < HALO_X + TILE_W) {
            int gy = y0 - HALO_Y + r, gx = x0 - HALO_X + x;
            float4 o{v[q][0], v[q][1], v[q][2], v[q][3]};
            if (SUB_SHIFT) { o.x -= shift; o.y -= shift; o.z -= shift; o.w -= shift; }
            *reinterpret_cast<float4*>(dstb + gy * WW + gx) = o;
        }
    }
}

extern "C" void kernel_launch(void* const* d_in, const int* in_sizes, int n_in,
                              void* d_out, int out_size, void* d_ws, size_t ws_size,
                              hipStream_t stream) {
    const float* guide   = (const float*)d_in[0];
    const float* initial = (const float*)d_in[1];
    float* out    = (float*)d_out;
    float* out_y  = out;
    float* out_cv = out + N_DEPTH;
    float* out_ch = out + N_DEPTH + N_CV;

    float* wsf    = (float*)d_ws;
    float* keyf   = wsf;                       // slot 0 (fallback only)
    float* bufA   = wsf + 64;
    float* bufB   = bufA + N_DEPTH;
    unsigned* flags = (unsigned*)(bufB + N_DEPTH);     // 256
    float* partials = (float*)(flags + 256);           // 256

    const size_t need = (size_t)(64 + 2 * N_DEPTH + 512) * 4;
    const bool fast = ws_size >= need;

    hipLaunchKernelGGL(coeff_min_kernel, dim3(NCO_BLK + 256), dim3(256), 0, stream,
                       guide, initial, out_cv, out_ch, partials, flags);

    if (fast) {
        // Regular launch: co-residency is structural (256 blocks <= 256 CUs;
        // 59KB LDS, 9 waves, 64 VGPR).
        hipLaunchKernelGGL(diffuse_persist, dim3(256), dim3(NTF), 0, stream,
                           initial, out_y, bufA, bufB, out_cv, out_ch,
                           partials, flags);
        return;
    }

    // fallback: derive shift then R2-verified relaunch loop
    hipLaunchKernelGGL(key_from_partials, dim3(1), dim3(256), 0, stream,
                       partials, keyf);
    float* bufs[2] = {bufA, bufB};
    for (int k = 0; k < NSS; ++k) {
        const float* src = (k == 0) ? initial : bufs[(k + 1) & 1];
        float*       dst = (k == NSS - 1) ? out_y : bufs[k & 1];
        if (k == 0)
            hipLaunchKernelGGL((step_fused<true, false>), dim3(256), dim3(256), 0,
                               stream, src, dst, out_cv, out_ch, keyf);
        else if (k == NSS - 1)
            hipLaunchKernelGGL((step_fused<false, true>), dim3(256), dim3(256), 0,
                               stream, src, dst, out_cv, out_ch, keyf);
        else
            hipLaunchKernelGGL((step_fused<false, false>), dim3(256), dim3(256), 0,
                               stream, src, dst, out_cv, out_ch, keyf);
    }
}